// Round 12
// baseline (411.656 us; speedup 1.0000x reference)
//
#include <hip/hip_runtime.h>
#include <cstdint>
#include <cstddef>

#define DF 128      // feature dim
#define HATT 64     // attention hidden dim
#define SL 64       // edge slices for graph prep
#define RPB 1280    // max rows per range-block (LDS counters)

static inline int divup(int a, int b) { return (a + b - 1) / b; }

typedef int vint4 __attribute__((ext_vector_type(4)));   // nontemporal-compatible

// ---------------- L2 warming (spmm kernels only) ----------------
__device__ __forceinline__ void warm_table(const float* t, int nf4, int b, int nb) {
    int slice = (nf4 + nb - 1) / nb;
    int start = b * slice;
    int end = min(start + slice, nf4);
    float acc = 0.f;
    for (int i = start + (int)threadIdx.x; i < end; i += 256) {
        float4 v = ((const float4*)t)[i];
        acc += v.x + v.y + v.z + v.w;
    }
    asm volatile("" :: "v"(acc));
}

// ---------------- graph prep bodies ----------------
__device__ __forceinline__ void hist2_body(int bid, const int* __restrict__ row,
                                           int* __restrict__ cnt2,
                                           int E, int n, int ranges, int rpb, int es) {
    int rb = bid % ranges;
    int s  = bid / ranges;
    int lo = rb * rpb, hi = min(lo + rpb, n);
    int rows = hi - lo;
    __shared__ int lc[RPB];
    for (int j = threadIdx.x; j < rows; j += 256) lc[j] = 0;
    __syncthreads();
    int i0 = s * es, i1 = min(i0 + es, E);
    const vint4* rv = (const vint4*)row;
    for (int j = i0 / 4 + threadIdx.x; j < i1 / 4; j += 256) {
        vint4 r4 = __builtin_nontemporal_load(rv + j);
        if (r4.x >= lo && r4.x < hi) atomicAdd(&lc[r4.x - lo], 1);
        if (r4.y >= lo && r4.y < hi) atomicAdd(&lc[r4.y - lo], 1);
        if (r4.z >= lo && r4.z < hi) atomicAdd(&lc[r4.z - lo], 1);
        if (r4.w >= lo && r4.w < hi) atomicAdd(&lc[r4.w - lo], 1);
    }
    __syncthreads();
    for (int j = threadIdx.x; j < rows; j += 256) cnt2[(size_t)s * n + lo + j] = lc[j];
}

__device__ __forceinline__ void split_x_body(int bid, const float* __restrict__ x,
                                             float* __restrict__ xA,
                                             float* __restrict__ xB,
                                             float* __restrict__ sqn, int n) {
    int wid = bid * 4 + (threadIdx.x >> 6);
    int lane = threadIdx.x & 63;
    if (wid >= n) return;
    float v0 = x[(size_t)wid * DF + lane];
    float v1 = x[(size_t)wid * DF + 64 + lane];
    xA[(size_t)wid * 64 + lane] = v0;
    xB[(size_t)wid * 64 + lane] = v1;
    float s = v0 * v0 + v1 * v1;
    for (int off = 32; off; off >>= 1) s += __shfl_xor(s, off);
    if (lane == 0) sqn[wid] = s;
}

__global__ __launch_bounds__(256) void prep_split_kernel(const int* __restrict__ row,
                                                         int* __restrict__ cnt2,
                                                         const float* __restrict__ x,
                                                         float* __restrict__ xA,
                                                         float* __restrict__ xB,
                                                         float* __restrict__ sqn,
                                                         int E, int n, int ranges, int rpb,
                                                         int es, int prepBlocks) {
    if ((int)blockIdx.x < prepBlocks)
        hist2_body(blockIdx.x, row, cnt2, E, n, ranges, rpb, es);
    else
        split_x_body(blockIdx.x - prepBlocks, x, xA, xB, sqn, n);
}

__global__ __launch_bounds__(256) void scanRT_kernel(int* __restrict__ cnt2,
                                                     int* __restrict__ tot, int n) {
    __shared__ int tile[SL][65];
    int r0 = blockIdx.x * 64;
    int w = threadIdx.x >> 6;
    int lane = threadIdx.x & 63;
    int rows = min(64, n - r0);
    for (int s = w; s < SL; s += 4) {
        int v = (lane < rows) ? cnt2[(size_t)s * n + r0 + lane] : 0;
        tile[s][lane] = v;
    }
    __syncthreads();
    int t = threadIdx.x;
    if (t < rows) {
        int run = 0;
#pragma unroll
        for (int s = 0; s < SL; ++s) {
            int v = tile[s][t];
            tile[s][t] = run;
            run += v;
        }
        tot[r0 + t] = run;
    }
    __syncthreads();
    for (int s = w; s < SL; s += 4) {
        if (lane < rows) cnt2[(size_t)s * n + r0 + lane] = tile[s][lane];
    }
}

__global__ __launch_bounds__(1024) void scanT_kernel(const int* __restrict__ tot,
                                                     int* __restrict__ row_ptr, int n) {
    __shared__ int sums[1024];
    int t = threadIdx.x;
    int chunk = (n + 1023) >> 10;
    int start = t * chunk, end = min(start + chunk, n);
    int s = 0;
    for (int r = start; r < end; ++r) s += tot[r];
    sums[t] = s;
    __syncthreads();
    for (int off = 1; off < 1024; off <<= 1) {
        int v = (t >= off) ? sums[t - off] : 0;
        __syncthreads();
        sums[t] += v;
        __syncthreads();
    }
    int run = sums[t] - s;
    for (int r = start; r < end; ++r) {
        row_ptr[r] = run;
        run += tot[r];
    }
    if (t == 1023) row_ptr[n] = sums[1023];
}

__device__ __forceinline__ void scatter2_body(int bid, const int* __restrict__ row,
                                              const int* __restrict__ col,
                                              const int* __restrict__ cnt2,
                                              const int* __restrict__ row_ptr,
                                              unsigned short* __restrict__ col_s,
                                              int E, int n, int ranges, int rpb, int es) {
    int rb = bid % ranges;
    int s  = bid / ranges;
    int lo = rb * rpb, hi = min(lo + rpb, n);
    int rows = hi - lo;
    __shared__ int cur[RPB];
    for (int j = threadIdx.x; j < rows; j += 256)
        cur[j] = cnt2[(size_t)s * n + lo + j] + row_ptr[lo + j];
    __syncthreads();
    int i0 = s * es, i1 = min(i0 + es, E);
    const vint4* rv = (const vint4*)row;
    const vint4* cv = (const vint4*)col;
    for (int j = i0 / 4 + threadIdx.x; j < i1 / 4; j += 256) {
        vint4 r4 = __builtin_nontemporal_load(rv + j);
        bool b0 = (r4.x >= lo && r4.x < hi);
        bool b1 = (r4.y >= lo && r4.y < hi);
        bool b2 = (r4.z >= lo && r4.z < hi);
        bool b3 = (r4.w >= lo && r4.w < hi);
        if (b0 | b1 | b2 | b3) {
            vint4 c4 = __builtin_nontemporal_load(cv + j);
            if (b0) { int p = atomicAdd(&cur[r4.x - lo], 1); col_s[p] = (unsigned short)c4.x; }
            if (b1) { int p = atomicAdd(&cur[r4.y - lo], 1); col_s[p] = (unsigned short)c4.y; }
            if (b2) { int p = atomicAdd(&cur[r4.z - lo], 1); col_s[p] = (unsigned short)c4.z; }
            if (b3) { int p = atomicAdd(&cur[r4.w - lo], 1); col_s[p] = (unsigned short)c4.w; }
        }
    }
}

// ---------------- dense matmul body ----------------
__device__ __forceinline__ void mm_body(int bid, const float* __restrict__ inA,
                                        const float* __restrict__ inB, int strideIn,
                                        const float* __restrict__ W,
                                        float* __restrict__ hA, float* __restrict__ hB, int n) {
    int wid = bid * 4 + (threadIdx.x >> 6);
    int lane = threadIdx.x & 63;
    int i0 = wid * 4;
    if (i0 >= n) return;
    float v0[4], v1[4];
#pragma unroll
    for (int r = 0; r < 4; ++r) {
        int i = i0 + r;
        if (i < n) { v0[r] = inA[(size_t)i * strideIn + lane]; v1[r] = inB[(size_t)i * strideIn + lane]; }
        else { v0[r] = 0.f; v1[r] = 0.f; }
    }
    float acc0[4] = {0.f, 0.f, 0.f, 0.f};
    float acc1[4] = {0.f, 0.f, 0.f, 0.f};
#pragma unroll 4
    for (int k = 0; k < 64; ++k) {
        float w0 = W[k * DF + lane];
        float w1 = W[k * DF + 64 + lane];
#pragma unroll
        for (int r = 0; r < 4; ++r) {
            float a = __shfl(v0[r], k);
            acc0[r] = fmaf(a, w0, acc0[r]);
            acc1[r] = fmaf(a, w1, acc1[r]);
        }
    }
#pragma unroll 4
    for (int k = 0; k < 64; ++k) {
        float w0 = W[(k + 64) * DF + lane];
        float w1 = W[(k + 64) * DF + 64 + lane];
#pragma unroll
        for (int r = 0; r < 4; ++r) {
            float a = __shfl(v1[r], k);
            acc0[r] = fmaf(a, w0, acc0[r]);
            acc1[r] = fmaf(a, w1, acc1[r]);
        }
    }
#pragma unroll
    for (int r = 0; r < 4; ++r) {
        int i = i0 + r;
        if (i < n) { hA[(size_t)i * 64 + lane] = acc0[r]; hB[(size_t)i * 64 + lane] = acc1[r]; }
    }
}

// merged: scatter2 (blocks [0, prepBlocks)) || mm x@W1 (rest)
__global__ __launch_bounds__(256) void scatmm_kernel(const int* __restrict__ row,
                                                     const int* __restrict__ col,
                                                     const int* __restrict__ cnt2,
                                                     const int* __restrict__ row_ptr,
                                                     unsigned short* __restrict__ col_s,
                                                     const float* __restrict__ x,
                                                     const float* __restrict__ W1,
                                                     float* __restrict__ hA,
                                                     float* __restrict__ hB,
                                                     int E, int n, int ranges, int rpb,
                                                     int es, int prepBlocks) {
    if ((int)blockIdx.x < prepBlocks)
        scatter2_body(blockIdx.x, row, col, cnt2, row_ptr, col_s, E, n, ranges, rpb, es);
    else
        mm_body(blockIdx.x - prepBlocks, x, x + 64, DF, W1, hA, hB, n);
}

// ---------------- fused edge weights: 32 lanes per edge, full 128-dot ----------------
// lanes 0-15 of each 32-group gather the tA row, lanes 16-31 the tB row; 5-step
// butterfly (xor16 merges the half-dots) gives the full dot on all 32 lanes.
// Group sg = lane>>5 handles edges base + sg*32 + it; lane L keeps edge base+L.

// layer 1: both metrics + fused degrees
__global__ __launch_bounds__(256) void edgew1f_kernel(const float* __restrict__ xA,
                                                      const float* __restrict__ xB,
                                                      const float* __restrict__ sqn,
                                                      const unsigned short* __restrict__ col_s,
                                                      const int* __restrict__ row_ptr,
                                                      float* __restrict__ wA,
                                                      float* __restrict__ wB,
                                                      float* __restrict__ disA,
                                                      float* __restrict__ disB, int n) {
    int wid = blockIdx.x * 4 + (threadIdx.x >> 6);
    int lane = threadIdx.x & 63;
    if (wid >= n) return;
    int sub = lane & 15;
    const float* tH = ((lane >> 4) & 1) ? xB : xA;
    int s = row_ptr[wid], e = row_ptr[wid + 1];
    float4 a = ((const float4*)(tH + (size_t)wid * 64))[sub];
    float na = sqn[wid];
    float accA = 0.f, accB = 0.f;
    for (int base = s; base < e; base += 64) {
        int m = e - base; if (m > 64) m = 64;
        int cc = 0;
        if (lane < m) cc = (int)col_s[base + lane];
        float dkeep = 0.f;
#define EW1F_BODY(CHK)                                                       \
        _Pragma("unroll")                                                    \
        for (int it = 0; it < 32; ++it) {                                    \
            int idx = (lane & 32) + it;                                      \
            int c = __shfl(cc, idx);                                         \
            if (CHK) {                                                       \
                float4 b = ((const float4*)(tH + (size_t)c * 64))[sub];      \
                float d = a.x * b.x + a.y * b.y + a.z * b.z + a.w * b.w;     \
                d += __shfl_xor(d, 16); d += __shfl_xor(d, 8);               \
                d += __shfl_xor(d, 4);  d += __shfl_xor(d, 2);               \
                d += __shfl_xor(d, 1);                                       \
                dkeep = ((lane & 31) == it) ? d : dkeep;                     \
            }                                                                \
        }
        if (m == 64) { EW1F_BODY(true) } else { EW1F_BODY(idx < m) }
#undef EW1F_BODY
        if (lane < m) {
            float d = dkeep;
            float nb = sqn[cc];
            float cw = d / fmaxf(sqrtf(na * nb), 1e-8f);
            float ew = sqrtf(fmaxf(na + nb - 2.f * d, 0.f) + 1e-12f);
            wA[base + lane] = cw;
            wB[base + lane] = ew;
            accA += cw;
            accB += ew;
        }
    }
#pragma unroll
    for (int off = 32; off; off >>= 1) {
        accA += __shfl_xor(accA, off);
        accB += __shfl_xor(accB, off);
    }
    if (lane == 0) {
        float dA = 1.f + accA;
        disA[wid] = (dA > 0.f) ? rsqrtf(fmaxf(dA, 1e-12f)) : 0.f;
        float dB = 1.f + accB;
        disB[wid] = (dB > 0.f) ? rsqrtf(fmaxf(dB, 1e-12f)) : 0.f;
    }
}

// layer 2 fused edgew body, branch br: 0 = cosine on x1 -> wsA,disA; 1 = euclid on x2 -> wsB,disB
__device__ __forceinline__ void edgew2f_body(int bid, int br,
                                             const float* __restrict__ tAt,
                                             const float* __restrict__ tBt,
                                             const float* __restrict__ sqA,
                                             const float* __restrict__ sqB,
                                             const unsigned short* __restrict__ col_s,
                                             const int* __restrict__ row_ptr,
                                             float* __restrict__ wOut,
                                             float* __restrict__ disOut, int n) {
    int wid = bid * 4 + (threadIdx.x >> 6);
    int lane = threadIdx.x & 63;
    if (wid >= n) return;
    int sub = lane & 15;
    const float* tH = ((lane >> 4) & 1) ? tBt : tAt;
    int s = row_ptr[wid], e = row_ptr[wid + 1];
    float4 a = ((const float4*)(tH + (size_t)wid * 64))[sub];
    float na = sqA[wid] + sqB[wid];
    float acc = 0.f;
    for (int base = s; base < e; base += 64) {
        int m = e - base; if (m > 64) m = 64;
        int cc = 0;
        if (lane < m) cc = (int)col_s[base + lane];
        float dkeep = 0.f;
#define EW2F_BODY(CHK)                                                       \
        _Pragma("unroll")                                                    \
        for (int it = 0; it < 32; ++it) {                                    \
            int idx = (lane & 32) + it;                                      \
            int c = __shfl(cc, idx);                                         \
            if (CHK) {                                                       \
                float4 b = ((const float4*)(tH + (size_t)c * 64))[sub];      \
                float d = a.x * b.x + a.y * b.y + a.z * b.z + a.w * b.w;     \
                d += __shfl_xor(d, 16); d += __shfl_xor(d, 8);               \
                d += __shfl_xor(d, 4);  d += __shfl_xor(d, 2);               \
                d += __shfl_xor(d, 1);                                       \
                dkeep = ((lane & 31) == it) ? d : dkeep;                     \
            }                                                                \
        }
        if (m == 64) { EW2F_BODY(true) } else { EW2F_BODY(idx < m) }
#undef EW2F_BODY
        if (lane < m) {
            float d = dkeep;
            float nb = sqA[cc] + sqB[cc];
            float w;
            if (br == 0) w = d / fmaxf(sqrtf(na * nb), 1e-8f);
            else w = sqrtf(fmaxf(na + nb - 2.f * d, 0.f) + 1e-12f);
            wOut[base + lane] = w;
            acc += w;
        }
    }
#pragma unroll
    for (int off = 32; off; off >>= 1) acc += __shfl_xor(acc, off);
    if (lane == 0) {
        float dg = 1.f + acc;
        disOut[wid] = (dg > 0.f) ? rsqrtf(fmaxf(dg, 1e-12f)) : 0.f;
    }
}

// paired layer-2 mm body: branch parity
__device__ __forceinline__ void mm2_body(int bid, const float* __restrict__ x1A_,
                                         const float* __restrict__ x1B_,
                                         const float* __restrict__ x2A_,
                                         const float* __restrict__ x2B_,
                                         const float* __restrict__ W,
                                         float* __restrict__ h1A, float* __restrict__ h1B,
                                         float* __restrict__ h2A, float* __restrict__ h2B, int n) {
    int br = bid & 1;
    const float* inA = br ? x2A_ : x1A_;
    const float* inB = br ? x2B_ : x1B_;
    float* hA = br ? h2A : h1A;
    float* hB = br ? h2B : h1B;
    mm_body(bid >> 1, inA, inB, 64, W, hA, hB, n);
}

// merged: fused layer-2 edgew (blocks [0, pairBlocks), branch parity) || mm2 (rest)
__global__ __launch_bounds__(256) void ew2mm2_kernel(const float* __restrict__ x1A,
                                                     const float* __restrict__ x1B,
                                                     const float* __restrict__ x2A,
                                                     const float* __restrict__ x2B,
                                                     const float* __restrict__ sq1pA,
                                                     const float* __restrict__ sq1pB,
                                                     const float* __restrict__ sq2pA,
                                                     const float* __restrict__ sq2pB,
                                                     const unsigned short* __restrict__ col_s,
                                                     const int* __restrict__ row_ptr,
                                                     float* __restrict__ wsA,
                                                     float* __restrict__ wsB,
                                                     float* __restrict__ disA,
                                                     float* __restrict__ disB,
                                                     const float* __restrict__ W2,
                                                     float* __restrict__ h1A, float* __restrict__ h1B,
                                                     float* __restrict__ h2A, float* __restrict__ h2B,
                                                     int n, int pairBlocks) {
    if ((int)blockIdx.x < pairBlocks) {
        int br = blockIdx.x & 1;
        if (br == 0)
            edgew2f_body(blockIdx.x >> 1, 0, x1A, x1B, sq1pA, sq1pB, col_s, row_ptr, wsA, disA, n);
        else
            edgew2f_body(blockIdx.x >> 1, 1, x2A, x2B, sq2pA, sq2pB, col_s, row_ptr, wsB, disB, n);
    } else {
        mm2_body(blockIdx.x - pairBlocks, x1A, x1B, x2A, x2B, W2, h1A, h1B, h2A, h2B, n);
    }
}

// ---------------- layer-1 dual SpMM, paired across halves, relu ----------------
__global__ __launch_bounds__(256) void spmm_l1_kernel(const float* __restrict__ hA,
                                                      const float* __restrict__ hB,
                                                      const float* __restrict__ wsA,
                                                      const float* __restrict__ wsB,
                                                      const unsigned short* __restrict__ col_s,
                                                      const float* __restrict__ disA,
                                                      const float* __restrict__ disB,
                                                      const int* __restrict__ row_ptr,
                                                      const float* __restrict__ bias,
                                                      float* __restrict__ x1A, float* __restrict__ x1B,
                                                      float* __restrict__ x2A, float* __restrict__ x2B,
                                                      float* __restrict__ sq1pA, float* __restrict__ sq1pB,
                                                      float* __restrict__ sq2pA, float* __restrict__ sq2pB,
                                                      int n, int nbTable) {
    int half = blockIdx.x & 1;
    const float* hH = half ? hB : hA;
    warm_table(hH, n * 16, blockIdx.x >> 1, nbTable);
    int wid = (blockIdx.x >> 1) * 4 + (threadIdx.x >> 6);
    int lane = threadIdx.x & 63;
    if (wid >= n) return;
    float* x1H = half ? x1B : x1A;
    float* x2H = half ? x2B : x2A;
    float* sq1 = half ? sq1pB : sq1pA;
    float* sq2 = half ? sq2pB : sq2pA;
    const float* biasH = bias + half * 64;
    int sub = lane & 15, g = lane >> 4;
    int s = row_ptr[wid], e = row_ptr[wid + 1];
    float diA = disA[wid], diB = disB[wid];
    float4 aA = make_float4(0.f, 0.f, 0.f, 0.f);
    float4 aB = make_float4(0.f, 0.f, 0.f, 0.f);
    for (int base = s; base < e; base += 64) {
        int m = e - base; if (m > 64) m = 64;
        int cc = 0; float wa = 0.f, wb = 0.f;
        if (lane < m) {
            cc = (int)col_s[base + lane];
            wa = wsA[base + lane] * disA[cc];
            wb = wsB[base + lane] * disB[cc];
        }
#define SPL1_BODY(CHK)                                                       \
        _Pragma("unroll")                                                    \
        for (int it = 0; it < 16; ++it) {                                    \
            int idx = it * 4 + g;                                            \
            int c = __shfl(cc, idx);                                         \
            float ceA = __shfl(wa, idx);                                     \
            float ceB = __shfl(wb, idx);                                     \
            if (CHK) {                                                       \
                float4 gv = ((const float4*)(hH + (size_t)c * 64))[sub];     \
                aA.x = fmaf(ceA, gv.x, aA.x); aA.y = fmaf(ceA, gv.y, aA.y);  \
                aA.z = fmaf(ceA, gv.z, aA.z); aA.w = fmaf(ceA, gv.w, aA.w);  \
                aB.x = fmaf(ceB, gv.x, aB.x); aB.y = fmaf(ceB, gv.y, aB.y);  \
                aB.z = fmaf(ceB, gv.z, aB.z); aB.w = fmaf(ceB, gv.w, aB.w);  \
            }                                                                \
        }
        if (m == 64) { SPL1_BODY(true) } else { SPL1_BODY(idx < m) }
#undef SPL1_BODY
    }
#pragma unroll
    for (int off = 16; off <= 32; off <<= 1) {
        aA.x += __shfl_xor(aA.x, off); aA.y += __shfl_xor(aA.y, off);
        aA.z += __shfl_xor(aA.z, off); aA.w += __shfl_xor(aA.w, off);
        aB.x += __shfl_xor(aB.x, off); aB.y += __shfl_xor(aB.y, off);
        aB.z += __shfl_xor(aB.z, off); aB.w += __shfl_xor(aB.w, off);
    }
    float4 hv = ((const float4*)(hH + (size_t)wid * 64))[sub];
    float4 bb = ((const float4*)biasH)[sub];
    float4 oA, oB;
    oA.x = fmaxf(diA * (aA.x + diA * hv.x) + bb.x, 0.f);
    oA.y = fmaxf(diA * (aA.y + diA * hv.y) + bb.y, 0.f);
    oA.z = fmaxf(diA * (aA.z + diA * hv.z) + bb.z, 0.f);
    oA.w = fmaxf(diA * (aA.w + diA * hv.w) + bb.w, 0.f);
    oB.x = fmaxf(diB * (aB.x + diB * hv.x) + bb.x, 0.f);
    oB.y = fmaxf(diB * (aB.y + diB * hv.y) + bb.y, 0.f);
    oB.z = fmaxf(diB * (aB.z + diB * hv.z) + bb.z, 0.f);
    oB.w = fmaxf(diB * (aB.w + diB * hv.w) + bb.w, 0.f);
    if (g == 0) {
        ((float4*)(x1H + (size_t)wid * 64))[sub] = oA;
        ((float4*)(x2H + (size_t)wid * 64))[sub] = oB;
    }
    float sA = oA.x * oA.x + oA.y * oA.y + oA.z * oA.z + oA.w * oA.w;
    float sB = oB.x * oB.x + oB.y * oB.y + oB.z * oB.z + oB.w * oB.w;
#pragma unroll
    for (int off = 8; off; off >>= 1) {
        sA += __shfl_xor(sA, off);
        sB += __shfl_xor(sB, off);
    }
    if (lane == 0) { sq1[wid] = sA; sq2[wid] = sB; }
}

// ---------------- layer-2 SpMM: 4-way parity (branch x half) ----------------
__global__ __launch_bounds__(256) void spmm2q_kernel(const float* __restrict__ h1A,
                                                     const float* __restrict__ h1B,
                                                     const float* __restrict__ h2A,
                                                     const float* __restrict__ h2B,
                                                     const float* __restrict__ wsA,
                                                     const float* __restrict__ wsB,
                                                     const unsigned short* __restrict__ col_s,
                                                     const float* __restrict__ disA,
                                                     const float* __restrict__ disB,
                                                     const int* __restrict__ row_ptr,
                                                     const float* __restrict__ bias,
                                                     float* __restrict__ x1A, float* __restrict__ x1B,
                                                     float* __restrict__ x2A, float* __restrict__ x2B,
                                                     int n, int nbTable) {
    int sel = blockIdx.x & 3;
    int br = sel & 1;      // 0 = cosine, 1 = euclid
    int half = sel >> 1;   // 0 = A, 1 = B
    const float* hH = br ? (half ? h2B : h2A) : (half ? h1B : h1A);
    warm_table(hH, n * 16, blockIdx.x >> 2, nbTable);
    const float* ws = br ? wsB : wsA;
    const float* dis = br ? disB : disA;
    float* outH = br ? (half ? x2B : x2A) : (half ? x1B : x1A);
    const float* biasH = bias + half * 64;
    int wid = (blockIdx.x >> 2) * 4 + (threadIdx.x >> 6);
    int lane = threadIdx.x & 63;
    if (wid >= n) return;
    int sub = lane & 15, g = lane >> 4;
    int s = row_ptr[wid], e = row_ptr[wid + 1];
    float di = dis[wid];
    float4 a = make_float4(0.f, 0.f, 0.f, 0.f);
    for (int base = s; base < e; base += 64) {
        int m = e - base; if (m > 64) m = 64;
        int cc = 0; float wv = 0.f;
        if (lane < m) {
            cc = (int)col_s[base + lane];
            wv = ws[base + lane] * dis[cc];
        }
#define SP2_BODY(CHK)                                                        \
        _Pragma("unroll")                                                    \
        for (int it = 0; it < 16; ++it) {                                    \
            int idx = it * 4 + g;                                            \
            int c = __shfl(cc, idx);                                         \
            float ce = __shfl(wv, idx);                                      \
            if (CHK) {                                                       \
                float4 gv = ((const float4*)(hH + (size_t)c * 64))[sub];     \
                a.x = fmaf(ce, gv.x, a.x); a.y = fmaf(ce, gv.y, a.y);        \
                a.z = fmaf(ce, gv.z, a.z); a.w = fmaf(ce, gv.w, a.w);        \
            }                                                                \
        }
        if (m == 64) { SP2_BODY(true) } else { SP2_BODY(idx < m) }
#undef SP2_BODY
    }
#pragma unroll
    for (int off = 16; off <= 32; off <<= 1) {
        a.x += __shfl_xor(a.x, off); a.y += __shfl_xor(a.y, off);
        a.z += __shfl_xor(a.z, off); a.w += __shfl_xor(a.w, off);
    }
    if (g == 0) {
        float4 hv = ((const float4*)(hH + (size_t)wid * 64))[sub];
        float4 bb = ((const float4*)biasH)[sub];
        float4 o;
        o.x = di * (a.x + di * hv.x) + bb.x;
        o.y = di * (a.y + di * hv.y) + bb.y;
        o.z = di * (a.z + di * hv.z) + bb.z;
        o.w = di * (a.w + di * hv.w) + bb.w;
        ((float4*)(outH + (size_t)wid * 64))[sub] = o;
    }
}

// ---------------- semantic attention fusion ----------------
__global__ __launch_bounds__(256) void attn_kernel(const float* __restrict__ x1A,
                                                   const float* __restrict__ x1B,
                                                   const float* __restrict__ x2A,
                                                   const float* __restrict__ x2B,
                                                   const float* __restrict__ A1,
                                                   const float* __restrict__ ab1,
                                                   const float* __restrict__ A2,
                                                   float* __restrict__ out, int n) {
    __shared__ float sA1[DF * HATT];
    __shared__ float sA2[HATT];
    __shared__ float sab[HATT];
    int tid = threadIdx.x;
    for (int i = tid; i < DF * HATT; i += 256) sA1[i] = A1[i];
    if (tid < HATT) { sA2[tid] = A2[tid]; sab[tid] = ab1[tid]; }
    __syncthreads();
    int lane = tid & 63;
    int wib = tid >> 6;
    int wid = blockIdx.x * 4 + wib;
    int nw = gridDim.x * 4;
    for (int i = wid; i < n; i += nw) {
        float u0 = x1A[(size_t)i * 64 + lane], u1 = x1B[(size_t)i * 64 + lane];
        float v0 = x2A[(size_t)i * 64 + lane], v1 = x2B[(size_t)i * 64 + lane];
        float acc1 = 0.f, acc2 = 0.f;
#pragma unroll 4
        for (int d = 0; d < 64; ++d) {
            float w = sA1[d * HATT + lane];
            acc1 = fmaf(__shfl(u0, d), w, acc1);
            acc2 = fmaf(__shfl(v0, d), w, acc2);
        }
#pragma unroll 4
        for (int d = 0; d < 64; ++d) {
            float w = sA1[(d + 64) * HATT + lane];
            acc1 = fmaf(__shfl(u1, d), w, acc1);
            acc2 = fmaf(__shfl(v1, d), w, acc2);
        }
        float t1 = tanhf(acc1 + sab[lane]) * sA2[lane];
        float t2 = tanhf(acc2 + sab[lane]) * sA2[lane];
        for (int off = 32; off; off >>= 1) {
            t1 += __shfl_xor(t1, off);
            t2 += __shfl_xor(t2, off);
        }
        float mx = fmaxf(t1, t2);
        float e1 = expf(t1 - mx), e2 = expf(t2 - mx);
        float inv = 1.f / (e1 + e2);
        float be1 = e1 * inv, be2 = e2 * inv;
        out[(size_t)i * DF + lane] = be1 * u0 + be2 * v0;
        out[(size_t)i * DF + 64 + lane] = be1 * u1 + be2 * v1;
    }
}

// ---------------- launch ----------------

extern "C" void kernel_launch(void* const* d_in, const int* in_sizes, int n_in,
                              void* d_out, int out_size, void* d_ws, size_t ws_size,
                              hipStream_t stream) {
    const float* x  = (const float*)d_in[0];
    const int* row  = (const int*)d_in[1];
    const int* col  = (const int*)d_in[2];
    const float* W1 = (const float*)d_in[3];
    const float* b1 = (const float*)d_in[4];
    const float* W2 = (const float*)d_in[5];
    const float* b2 = (const float*)d_in[6];
    const float* A1 = (const float*)d_in[7];
    const float* ab1= (const float*)d_in[8];
    const float* A2 = (const float*)d_in[9];
    const int N = in_sizes[0] / DF;
    const int E = in_sizes[1];
    float* out = (float*)d_out;

    char* p = (char*)d_ws;
    auto alloc_b = [&](size_t bytes) -> char* {
        char* r = p;
        p += (bytes + 255) & ~(size_t)255;
        return r;
    };
    float* xA    = (float*)alloc_b((size_t)N * 64 * 4);
    float* xB    = (float*)alloc_b((size_t)N * 64 * 4);
    float* hA    = (float*)alloc_b((size_t)N * 64 * 4);   // also h1A
    float* hB    = (float*)alloc_b((size_t)N * 64 * 4);   // also h1B
    float* h2A   = (float*)alloc_b((size_t)N * 64 * 4);
    float* h2B   = (float*)alloc_b((size_t)N * 64 * 4);
    float* x1A   = (float*)alloc_b((size_t)N * 64 * 4);
    float* x1B   = (float*)alloc_b((size_t)N * 64 * 4);
    float* x2A   = (float*)alloc_b((size_t)N * 64 * 4);
    float* x2B   = (float*)alloc_b((size_t)N * 64 * 4);
    float* wsA   = (float*)alloc_b((size_t)E * 4);
    float* wsB   = (float*)alloc_b((size_t)E * 4);
    float* disA  = (float*)alloc_b((size_t)N * 4);
    float* disB  = (float*)alloc_b((size_t)N * 4);
    float* sqnx  = (float*)alloc_b((size_t)N * 4);
    float* sq1pA = (float*)alloc_b((size_t)N * 4);
    float* sq1pB = (float*)alloc_b((size_t)N * 4);
    float* sq2pA = (float*)alloc_b((size_t)N * 4);
    float* sq2pB = (float*)alloc_b((size_t)N * 4);
    int* cnt2    = (int*)alloc_b((size_t)SL * N * 4);
    int* tot     = (int*)alloc_b((size_t)N * 4);
    int* rowptr  = (int*)alloc_b((size_t)(N + 1) * 4);
    unsigned short* col_s = (unsigned short*)alloc_b((size_t)E * 2);
    (void)ws_size; (void)n_in; (void)out_size;

    const int nodeBlocks  = divup(N * 64, 256);   // 2500
    const int pairBlocks  = 2 * nodeBlocks;       // 5000
    const int quadBlocks  = 4 * nodeBlocks;       // 10000
    const int mmBlocks    = divup(divup(N, 4), 4);
    const int mm2Blocks   = 2 * mmBlocks;
    const int ranges = divup(N, RPB);
    const int rpb    = divup(N, ranges);
    int es = divup(E, SL); es = (es + 3) & ~3;
    const int prepBlocks = ranges * SL;

    // prep: hist2 || split_x
    prep_split_kernel<<<prepBlocks + nodeBlocks, 256, 0, stream>>>(row, cnt2, x, xA, xB, sqnx,
                                                                   E, N, ranges, rpb, es, prepBlocks);
    scanRT_kernel<<<divup(N, 64), 256, 0, stream>>>(cnt2, tot, N);
    scanT_kernel<<<1, 1024, 0, stream>>>(tot, rowptr, N);

    // scatter2 || mm (x @ W1)
    scatmm_kernel<<<prepBlocks + mmBlocks, 256, 0, stream>>>(row, col, cnt2, rowptr, col_s,
                                                             x, W1, hA, hB,
                                                             E, N, ranges, rpb, es, prepBlocks);

    // layer-1 fused edge weights (single pass, both metrics) + degrees
    edgew1f_kernel<<<nodeBlocks, 256, 0, stream>>>(xA, xB, sqnx, col_s, rowptr,
                                                   wsA, wsB, disA, disB, N);

    // layer-1 dual SpMM, both halves in one launch
    spmm_l1_kernel<<<pairBlocks, 256, 0, stream>>>(hA, hB, wsA, wsB, col_s, disA, disB,
                                                   rowptr, b1, x1A, x1B, x2A, x2B,
                                                   sq1pA, sq1pB, sq2pA, sq2pB, N, nodeBlocks);

    // layer-2: fused edge weights (branch parity) || mm2 (branch parity)
    ew2mm2_kernel<<<pairBlocks + mm2Blocks, 256, 0, stream>>>(x1A, x1B, x2A, x2B,
                                                              sq1pA, sq1pB, sq2pA, sq2pB,
                                                              col_s, rowptr,
                                                              wsA, wsB, disA, disB,
                                                              W2, hA, hB, h2A, h2B,
                                                              N, pairBlocks);

    // layer-2 SpMM: single 4-way launch (branch x half)
    spmm2q_kernel<<<quadBlocks, 256, 0, stream>>>(hA, hB, h2A, h2B, wsA, wsB, col_s,
                                                  disA, disB, rowptr, b2,
                                                  x1A, x1B, x2A, x2B, N, nodeBlocks);

    // semantic attention fusion -> out
    attn_kernel<<<divup(N, 4), 256, 0, stream>>>(x1A, x1B, x2A, x2B, A1, ab1, A2, out, N);
}

// Round 13
// 356.758 us; speedup vs baseline: 1.1539x; 1.1539x over previous
//
#include <hip/hip_runtime.h>
#include <cstdint>
#include <cstddef>

#define DF 128      // feature dim
#define HATT 64     // attention hidden dim
#define SL 64       // edge slices for graph prep
#define RPB 1280    // max rows per range-block (LDS counters)

static inline int divup(int a, int b) { return (a + b - 1) / b; }

typedef int vint4 __attribute__((ext_vector_type(4)));              // nontemporal-compatible
typedef unsigned short vus4 __attribute__((ext_vector_type(4)));    // bf16x4 gather

// bf16 round-to-nearest-even (values only used in LINEAR aggregation; the
// weight->deg->rsqrt chain stays fp32 -- bf16 there was catastrophic, round 2)
static __device__ __forceinline__ unsigned short f2bf(float f) {
    unsigned int u = __float_as_uint(f);
    u = (u + 0x7FFFu + ((u >> 16) & 1u)) >> 16;
    return (unsigned short)u;
}
static __device__ __forceinline__ float bf2f(unsigned short b) {
    return __uint_as_float(((unsigned int)b) << 16);
}

// ---------------- graph prep ----------------
__global__ __launch_bounds__(256) void hist2_kernel(const int* __restrict__ row,
                                                    int* __restrict__ cnt2,
                                                    int E, int n, int ranges, int rpb, int es) {
    int rb = blockIdx.x % ranges;
    int s  = blockIdx.x / ranges;
    int lo = rb * rpb, hi = min(lo + rpb, n);
    int rows = hi - lo;
    __shared__ int lc[RPB];
    for (int j = threadIdx.x; j < rows; j += 256) lc[j] = 0;
    __syncthreads();
    int i0 = s * es, i1 = min(i0 + es, E);
    const vint4* rv = (const vint4*)row;
    for (int j = i0 / 4 + threadIdx.x; j < i1 / 4; j += 256) {
        vint4 r4 = __builtin_nontemporal_load(rv + j);
        if (r4.x >= lo && r4.x < hi) atomicAdd(&lc[r4.x - lo], 1);
        if (r4.y >= lo && r4.y < hi) atomicAdd(&lc[r4.y - lo], 1);
        if (r4.z >= lo && r4.z < hi) atomicAdd(&lc[r4.z - lo], 1);
        if (r4.w >= lo && r4.w < hi) atomicAdd(&lc[r4.w - lo], 1);
    }
    __syncthreads();
    for (int j = threadIdx.x; j < rows; j += 256) cnt2[(size_t)s * n + lo + j] = lc[j];
}

__global__ __launch_bounds__(256) void scanRT_kernel(int* __restrict__ cnt2,
                                                     int* __restrict__ tot, int n) {
    __shared__ int tile[SL][65];
    int r0 = blockIdx.x * 64;
    int w = threadIdx.x >> 6;
    int lane = threadIdx.x & 63;
    int rows = min(64, n - r0);
    for (int s = w; s < SL; s += 4) {
        int v = (lane < rows) ? cnt2[(size_t)s * n + r0 + lane] : 0;
        tile[s][lane] = v;
    }
    __syncthreads();
    int t = threadIdx.x;
    if (t < rows) {
        int run = 0;
#pragma unroll
        for (int s = 0; s < SL; ++s) {
            int v = tile[s][t];
            tile[s][t] = run;
            run += v;
        }
        tot[r0 + t] = run;
    }
    __syncthreads();
    for (int s = w; s < SL; s += 4) {
        if (lane < rows) cnt2[(size_t)s * n + r0 + lane] = tile[s][lane];
    }
}

__global__ __launch_bounds__(1024) void scanT_kernel(const int* __restrict__ tot,
                                                     int* __restrict__ row_ptr, int n) {
    __shared__ int sums[1024];
    int t = threadIdx.x;
    int chunk = (n + 1023) >> 10;
    int start = t * chunk, end = min(start + chunk, n);
    int s = 0;
    for (int r = start; r < end; ++r) s += tot[r];
    sums[t] = s;
    __syncthreads();
    for (int off = 1; off < 1024; off <<= 1) {
        int v = (t >= off) ? sums[t - off] : 0;
        __syncthreads();
        sums[t] += v;
        __syncthreads();
    }
    int run = sums[t] - s;
    for (int r = start; r < end; ++r) {
        row_ptr[r] = run;
        run += tot[r];
    }
    if (t == 1023) row_ptr[n] = sums[1023];
}

__global__ __launch_bounds__(256) void scatter2_kernel(const int* __restrict__ row,
                                                       const int* __restrict__ col,
                                                       const int* __restrict__ cnt2,
                                                       const int* __restrict__ row_ptr,
                                                       unsigned short* __restrict__ col_s,
                                                       int E, int n, int ranges, int rpb, int es) {
    int rb = blockIdx.x % ranges;
    int s  = blockIdx.x / ranges;
    int lo = rb * rpb, hi = min(lo + rpb, n);
    int rows = hi - lo;
    __shared__ int cur[RPB];
    for (int j = threadIdx.x; j < rows; j += 256)
        cur[j] = cnt2[(size_t)s * n + lo + j] + row_ptr[lo + j];
    __syncthreads();
    int i0 = s * es, i1 = min(i0 + es, E);
    const vint4* rv = (const vint4*)row;
    const vint4* cv = (const vint4*)col;
    for (int j = i0 / 4 + threadIdx.x; j < i1 / 4; j += 256) {
        vint4 r4 = __builtin_nontemporal_load(rv + j);
        bool b0 = (r4.x >= lo && r4.x < hi);
        bool b1 = (r4.y >= lo && r4.y < hi);
        bool b2 = (r4.z >= lo && r4.z < hi);
        bool b3 = (r4.w >= lo && r4.w < hi);
        if (b0 | b1 | b2 | b3) {
            vint4 c4 = __builtin_nontemporal_load(cv + j);
            if (b0) { int p = atomicAdd(&cur[r4.x - lo], 1); col_s[p] = (unsigned short)c4.x; }
            if (b1) { int p = atomicAdd(&cur[r4.y - lo], 1); col_s[p] = (unsigned short)c4.y; }
            if (b2) { int p = atomicAdd(&cur[r4.z - lo], 1); col_s[p] = (unsigned short)c4.z; }
            if (b3) { int p = atomicAdd(&cur[r4.w - lo], 1); col_s[p] = (unsigned short)c4.w; }
        }
    }
}

// ---------------- split x + squared norms ----------------
__global__ __launch_bounds__(256) void split_x_kernel(const float* __restrict__ x,
                                                      float* __restrict__ xA,
                                                      float* __restrict__ xB,
                                                      float* __restrict__ sqn, int n) {
    int wid = (blockIdx.x * blockDim.x + threadIdx.x) >> 6;
    int lane = threadIdx.x & 63;
    if (wid >= n) return;
    float v0 = x[(size_t)wid * DF + lane];
    float v1 = x[(size_t)wid * DF + 64 + lane];
    xA[(size_t)wid * 64 + lane] = v0;
    xB[(size_t)wid * 64 + lane] = v1;
    float s = v0 * v0 + v1 * v1;
    for (int off = 32; off; off >>= 1) s += __shfl_xor(s, off);
    if (lane == 0) sqn[wid] = s;
}

// ---------------- edge weights (fp32 tables, branchless keep) ----------------
__global__ __launch_bounds__(256) void edgewA_kernel(const float* __restrict__ tA,
                                                     const unsigned short* __restrict__ col_s,
                                                     const int* __restrict__ row_ptr,
                                                     float* __restrict__ dpart, int n) {
    int wid = (blockIdx.x * blockDim.x + threadIdx.x) >> 6;
    int lane = threadIdx.x & 63;
    if (wid >= n) return;
    int sub = lane & 15, g = lane >> 4;
    int s = row_ptr[wid], e = row_ptr[wid + 1];
    float4 a = ((const float4*)(tA + (size_t)wid * 64))[sub];
    for (int base = s; base < e; base += 64) {
        int m = e - base; if (m > 64) m = 64;
        int cc = 0;
        if (lane < m) cc = (int)col_s[base + lane];
        float dkeep = 0.f;
#define EWA_BODY(CHK)                                                        \
        _Pragma("unroll")                                                    \
        for (int it = 0; it < 16; ++it) {                                    \
            int idx = g * 16 + it;                                           \
            int c = __shfl(cc, idx);                                         \
            if (CHK) {                                                       \
                float4 b = ((const float4*)(tA + (size_t)c * 64))[sub];      \
                float d = a.x * b.x + a.y * b.y + a.z * b.z + a.w * b.w;     \
                d += __shfl_xor(d, 8); d += __shfl_xor(d, 4);                \
                d += __shfl_xor(d, 2); d += __shfl_xor(d, 1);                \
                dkeep = (sub == it) ? d : dkeep;                             \
            }                                                                \
        }
        if (m == 64) { EWA_BODY(true) } else { EWA_BODY(idx < m) }
#undef EWA_BODY
        if (lane < m) dpart[base + lane] = dkeep;
    }
}

__global__ __launch_bounds__(256) void edgewB1_kernel(const float* __restrict__ tB,
                                                      const float* __restrict__ sqn,
                                                      const unsigned short* __restrict__ col_s,
                                                      const int* __restrict__ row_ptr,
                                                      const float* __restrict__ dpart,
                                                      float* __restrict__ wA,
                                                      float* __restrict__ wB,
                                                      float* __restrict__ disA,
                                                      float* __restrict__ disB, int n) {
    int wid = (blockIdx.x * blockDim.x + threadIdx.x) >> 6;
    int lane = threadIdx.x & 63;
    if (wid >= n) return;
    int sub = lane & 15, g = lane >> 4;
    int s = row_ptr[wid], e = row_ptr[wid + 1];
    float4 a = ((const float4*)(tB + (size_t)wid * 64))[sub];
    float na = sqn[wid];
    float accA = 0.f, accB = 0.f;
    for (int base = s; base < e; base += 64) {
        int m = e - base; if (m > 64) m = 64;
        int cc = 0; float dp = 0.f;
        if (lane < m) {
            cc = (int)col_s[base + lane];
            dp = dpart[base + lane];
        }
        float dkeep = 0.f;
#define EWB1_BODY(CHK)                                                       \
        _Pragma("unroll")                                                    \
        for (int it = 0; it < 16; ++it) {                                    \
            int idx = g * 16 + it;                                           \
            int c = __shfl(cc, idx);                                         \
            if (CHK) {                                                       \
                float4 b = ((const float4*)(tB + (size_t)c * 64))[sub];      \
                float d = a.x * b.x + a.y * b.y + a.z * b.z + a.w * b.w;     \
                d += __shfl_xor(d, 8); d += __shfl_xor(d, 4);                \
                d += __shfl_xor(d, 2); d += __shfl_xor(d, 1);                \
                dkeep = (sub == it) ? d : dkeep;                             \
            }                                                                \
        }
        if (m == 64) { EWB1_BODY(true) } else { EWB1_BODY(idx < m) }
#undef EWB1_BODY
        if (lane < m) {
            float d = dkeep + dp;
            float nb = sqn[cc];
            float cw = d / fmaxf(sqrtf(na * nb), 1e-8f);
            float ew = sqrtf(fmaxf(na + nb - 2.f * d, 0.f) + 1e-12f);
            wA[base + lane] = cw;
            wB[base + lane] = ew;
            accA += cw;
            accB += ew;
        }
    }
#pragma unroll
    for (int off = 32; off; off >>= 1) {
        accA += __shfl_xor(accA, off);
        accB += __shfl_xor(accB, off);
    }
    if (lane == 0) {
        float dA = 1.f + accA;
        disA[wid] = (dA > 0.f) ? rsqrtf(fmaxf(dA, 1e-12f)) : 0.f;
        float dB = 1.f + accB;
        disB[wid] = (dB > 0.f) ? rsqrtf(fmaxf(dB, 1e-12f)) : 0.f;
    }
}

__global__ __launch_bounds__(256) void edgewA2_kernel(const float* __restrict__ t0,
                                                      const float* __restrict__ t1,
                                                      const unsigned short* __restrict__ col_s,
                                                      const int* __restrict__ row_ptr,
                                                      float* __restrict__ dp0,
                                                      float* __restrict__ dp1, int n) {
    int br = blockIdx.x & 1;
    int wid = (blockIdx.x >> 1) * 4 + (threadIdx.x >> 6);
    int lane = threadIdx.x & 63;
    if (wid >= n) return;
    const float* tA = br ? t1 : t0;
    float* dpart = br ? dp1 : dp0;
    int sub = lane & 15, g = lane >> 4;
    int s = row_ptr[wid], e = row_ptr[wid + 1];
    float4 a = ((const float4*)(tA + (size_t)wid * 64))[sub];
    for (int base = s; base < e; base += 64) {
        int m = e - base; if (m > 64) m = 64;
        int cc = 0;
        if (lane < m) cc = (int)col_s[base + lane];
        float dkeep = 0.f;
#define EWA2_BODY(CHK)                                                       \
        _Pragma("unroll")                                                    \
        for (int it = 0; it < 16; ++it) {                                    \
            int idx = g * 16 + it;                                           \
            int c = __shfl(cc, idx);                                         \
            if (CHK) {                                                       \
                float4 b = ((const float4*)(tA + (size_t)c * 64))[sub];      \
                float d = a.x * b.x + a.y * b.y + a.z * b.z + a.w * b.w;     \
                d += __shfl_xor(d, 8); d += __shfl_xor(d, 4);                \
                d += __shfl_xor(d, 2); d += __shfl_xor(d, 1);                \
                dkeep = (sub == it) ? d : dkeep;                             \
            }                                                                \
        }
        if (m == 64) { EWA2_BODY(true) } else { EWA2_BODY(idx < m) }
#undef EWA2_BODY
        if (lane < m) dpart[base + lane] = dkeep;
    }
}

__global__ __launch_bounds__(256) void edgewB2_kernel(const float* __restrict__ t0B,
                                                      const float* __restrict__ t1B,
                                                      const float* __restrict__ sq1pA,
                                                      const float* __restrict__ sq1pB,
                                                      const float* __restrict__ sq2pA,
                                                      const float* __restrict__ sq2pB,
                                                      const unsigned short* __restrict__ col_s,
                                                      const int* __restrict__ row_ptr,
                                                      const float* __restrict__ dp0,
                                                      const float* __restrict__ dp1,
                                                      float* __restrict__ wsA,
                                                      float* __restrict__ wsB,
                                                      float* __restrict__ disA,
                                                      float* __restrict__ disB, int n) {
    int br = blockIdx.x & 1;
    int wid = (blockIdx.x >> 1) * 4 + (threadIdx.x >> 6);
    int lane = threadIdx.x & 63;
    if (wid >= n) return;
    const float* tB = br ? t1B : t0B;
    const float* sqA = br ? sq2pA : sq1pA;
    const float* sqB = br ? sq2pB : sq1pB;
    const float* dpart = br ? dp1 : dp0;
    float* wOut = br ? wsB : wsA;
    float* disOut = br ? disB : disA;
    int sub = lane & 15, g = lane >> 4;
    int s = row_ptr[wid], e = row_ptr[wid + 1];
    float4 a = ((const float4*)(tB + (size_t)wid * 64))[sub];
    float na = sqA[wid] + sqB[wid];
    float acc = 0.f;
    for (int base = s; base < e; base += 64) {
        int m = e - base; if (m > 64) m = 64;
        int cc = 0; float dp = 0.f;
        if (lane < m) {
            cc = (int)col_s[base + lane];
            dp = dpart[base + lane];
        }
        float dkeep = 0.f;
#define EWB2_BODY(CHK)                                                       \
        _Pragma("unroll")                                                    \
        for (int it = 0; it < 16; ++it) {                                    \
            int idx = g * 16 + it;                                           \
            int c = __shfl(cc, idx);                                         \
            if (CHK) {                                                       \
                float4 b = ((const float4*)(tB + (size_t)c * 64))[sub];      \
                float d = a.x * b.x + a.y * b.y + a.z * b.z + a.w * b.w;     \
                d += __shfl_xor(d, 8); d += __shfl_xor(d, 4);                \
                d += __shfl_xor(d, 2); d += __shfl_xor(d, 1);                \
                dkeep = (sub == it) ? d : dkeep;                             \
            }                                                                \
        }
        if (m == 64) { EWB2_BODY(true) } else { EWB2_BODY(idx < m) }
#undef EWB2_BODY
        if (lane < m) {
            float d = dkeep + dp;
            float nb = sqA[cc] + sqB[cc];
            float w;
            if (br == 0) w = d / fmaxf(sqrtf(na * nb), 1e-8f);
            else w = sqrtf(fmaxf(na + nb - 2.f * d, 0.f) + 1e-12f);
            wOut[base + lane] = w;
            acc += w;
        }
    }
#pragma unroll
    for (int off = 32; off; off >>= 1) acc += __shfl_xor(acc, off);
    if (lane == 0) {
        float dg = 1.f + acc;
        disOut[wid] = (dg > 0.f) ? rsqrtf(fmaxf(dg, 1e-12f)) : 0.f;
    }
}

// ---------------- dense matmuls -> bf16 h tables ----------------
__global__ __launch_bounds__(256) void mm_kernel(const float* __restrict__ inA,
                                                 const float* __restrict__ inB,
                                                 int strideIn,
                                                 const float* __restrict__ W,
                                                 unsigned short* __restrict__ hA,
                                                 unsigned short* __restrict__ hB, int n) {
    int wid = (blockIdx.x * blockDim.x + threadIdx.x) >> 6;
    int lane = threadIdx.x & 63;
    int i0 = wid * 4;
    if (i0 >= n) return;
    float v0[4], v1[4];
#pragma unroll
    for (int r = 0; r < 4; ++r) {
        int i = i0 + r;
        if (i < n) { v0[r] = inA[(size_t)i * strideIn + lane]; v1[r] = inB[(size_t)i * strideIn + lane]; }
        else { v0[r] = 0.f; v1[r] = 0.f; }
    }
    float acc0[4] = {0.f, 0.f, 0.f, 0.f};
    float acc1[4] = {0.f, 0.f, 0.f, 0.f};
#pragma unroll 4
    for (int k = 0; k < 64; ++k) {
        float w0 = W[k * DF + lane];
        float w1 = W[k * DF + 64 + lane];
#pragma unroll
        for (int r = 0; r < 4; ++r) {
            float a = __shfl(v0[r], k);
            acc0[r] = fmaf(a, w0, acc0[r]);
            acc1[r] = fmaf(a, w1, acc1[r]);
        }
    }
#pragma unroll 4
    for (int k = 0; k < 64; ++k) {
        float w0 = W[(k + 64) * DF + lane];
        float w1 = W[(k + 64) * DF + 64 + lane];
#pragma unroll
        for (int r = 0; r < 4; ++r) {
            float a = __shfl(v1[r], k);
            acc0[r] = fmaf(a, w0, acc0[r]);
            acc1[r] = fmaf(a, w1, acc1[r]);
        }
    }
#pragma unroll
    for (int r = 0; r < 4; ++r) {
        int i = i0 + r;
        if (i < n) {
            hA[(size_t)i * 64 + lane] = f2bf(acc0[r]);
            hB[(size_t)i * 64 + lane] = f2bf(acc1[r]);
        }
    }
}

// paired layer-2 mm: branch parity
__global__ __launch_bounds__(256) void mm2_kernel(const float* __restrict__ x1A_,
                                                  const float* __restrict__ x1B_,
                                                  const float* __restrict__ x2A_,
                                                  const float* __restrict__ x2B_,
                                                  const float* __restrict__ W,
                                                  unsigned short* __restrict__ h1A, unsigned short* __restrict__ h1B,
                                                  unsigned short* __restrict__ h2A, unsigned short* __restrict__ h2B,
                                                  int n) {
    int br = blockIdx.x & 1;
    const float* inA = br ? x2A_ : x1A_;
    const float* inB = br ? x2B_ : x1B_;
    unsigned short* hA = br ? h2A : h1A;
    unsigned short* hB = br ? h2B : h1B;
    int wid = (blockIdx.x >> 1) * 4 + (threadIdx.x >> 6);
    int lane = threadIdx.x & 63;
    int i0 = wid * 4;
    if (i0 >= n) return;
    float v0[4], v1[4];
#pragma unroll
    for (int r = 0; r < 4; ++r) {
        int i = i0 + r;
        if (i < n) { v0[r] = inA[(size_t)i * 64 + lane]; v1[r] = inB[(size_t)i * 64 + lane]; }
        else { v0[r] = 0.f; v1[r] = 0.f; }
    }
    float acc0[4] = {0.f, 0.f, 0.f, 0.f};
    float acc1[4] = {0.f, 0.f, 0.f, 0.f};
#pragma unroll 4
    for (int k = 0; k < 64; ++k) {
        float w0 = W[k * DF + lane];
        float w1 = W[k * DF + 64 + lane];
#pragma unroll
        for (int r = 0; r < 4; ++r) {
            float a = __shfl(v0[r], k);
            acc0[r] = fmaf(a, w0, acc0[r]);
            acc1[r] = fmaf(a, w1, acc1[r]);
        }
    }
#pragma unroll 4
    for (int k = 0; k < 64; ++k) {
        float w0 = W[(k + 64) * DF + lane];
        float w1 = W[(k + 64) * DF + 64 + lane];
#pragma unroll
        for (int r = 0; r < 4; ++r) {
            float a = __shfl(v1[r], k);
            acc0[r] = fmaf(a, w0, acc0[r]);
            acc1[r] = fmaf(a, w1, acc1[r]);
        }
    }
#pragma unroll
    for (int r = 0; r < 4; ++r) {
        int i = i0 + r;
        if (i < n) {
            hA[(size_t)i * 64 + lane] = f2bf(acc0[r]);
            hB[(size_t)i * 64 + lane] = f2bf(acc1[r]);
        }
    }
}

// ---------------- layer-1 dual SpMM (bf16 h gathers), paired across halves, relu ----------------
__global__ __launch_bounds__(256) void spmm_l1_kernel(const unsigned short* __restrict__ hA,
                                                      const unsigned short* __restrict__ hB,
                                                      const float* __restrict__ wsA,
                                                      const float* __restrict__ wsB,
                                                      const unsigned short* __restrict__ col_s,
                                                      const float* __restrict__ disA,
                                                      const float* __restrict__ disB,
                                                      const int* __restrict__ row_ptr,
                                                      const float* __restrict__ bias,
                                                      float* __restrict__ x1A, float* __restrict__ x1B,
                                                      float* __restrict__ x2A, float* __restrict__ x2B,
                                                      float* __restrict__ sq1pA, float* __restrict__ sq1pB,
                                                      float* __restrict__ sq2pA, float* __restrict__ sq2pB,
                                                      int n) {
    int half = blockIdx.x & 1;
    int wid = (blockIdx.x >> 1) * 4 + (threadIdx.x >> 6);
    int lane = threadIdx.x & 63;
    if (wid >= n) return;
    const unsigned short* hH = half ? hB : hA;
    float* x1H = half ? x1B : x1A;
    float* x2H = half ? x2B : x2A;
    float* sq1 = half ? sq1pB : sq1pA;
    float* sq2 = half ? sq2pB : sq2pA;
    const float* biasH = bias + half * 64;
    int sub = lane & 15, g = lane >> 4;
    int s = row_ptr[wid], e = row_ptr[wid + 1];
    float diA = disA[wid], diB = disB[wid];
    float4 aA = make_float4(0.f, 0.f, 0.f, 0.f);
    float4 aB = make_float4(0.f, 0.f, 0.f, 0.f);
    for (int base = s; base < e; base += 64) {
        int m = e - base; if (m > 64) m = 64;
        int cc = 0; float wa = 0.f, wb = 0.f;
        if (lane < m) {
            cc = (int)col_s[base + lane];
            wa = wsA[base + lane] * disA[cc];
            wb = wsB[base + lane] * disB[cc];
        }
#define SPL1_BODY(CHK)                                                       \
        _Pragma("unroll")                                                    \
        for (int it = 0; it < 16; ++it) {                                    \
            int idx = it * 4 + g;                                            \
            int c = __shfl(cc, idx);                                         \
            float ceA = __shfl(wa, idx);                                     \
            float ceB = __shfl(wb, idx);                                     \
            if (CHK) {                                                       \
                vus4 gv = ((const vus4*)(hH + (size_t)c * 64))[sub];         \
                float g0 = bf2f(gv.x), g1 = bf2f(gv.y);                      \
                float g2 = bf2f(gv.z), g3 = bf2f(gv.w);                      \
                aA.x = fmaf(ceA, g0, aA.x); aA.y = fmaf(ceA, g1, aA.y);      \
                aA.z = fmaf(ceA, g2, aA.z); aA.w = fmaf(ceA, g3, aA.w);      \
                aB.x = fmaf(ceB, g0, aB.x); aB.y = fmaf(ceB, g1, aB.y);      \
                aB.z = fmaf(ceB, g2, aB.z); aB.w = fmaf(ceB, g3, aB.w);      \
            }                                                                \
        }
        if (m == 64) { SPL1_BODY(true) } else { SPL1_BODY(idx < m) }
#undef SPL1_BODY
    }
#pragma unroll
    for (int off = 16; off <= 32; off <<= 1) {
        aA.x += __shfl_xor(aA.x, off); aA.y += __shfl_xor(aA.y, off);
        aA.z += __shfl_xor(aA.z, off); aA.w += __shfl_xor(aA.w, off);
        aB.x += __shfl_xor(aB.x, off); aB.y += __shfl_xor(aB.y, off);
        aB.z += __shfl_xor(aB.z, off); aB.w += __shfl_xor(aB.w, off);
    }
    vus4 hvb = ((const vus4*)(hH + (size_t)wid * 64))[sub];
    float4 hv = make_float4(bf2f(hvb.x), bf2f(hvb.y), bf2f(hvb.z), bf2f(hvb.w));
    float4 bb = ((const float4*)biasH)[sub];
    float4 oA, oB;
    oA.x = fmaxf(diA * (aA.x + diA * hv.x) + bb.x, 0.f);
    oA.y = fmaxf(diA * (aA.y + diA * hv.y) + bb.y, 0.f);
    oA.z = fmaxf(diA * (aA.z + diA * hv.z) + bb.z, 0.f);
    oA.w = fmaxf(diA * (aA.w + diA * hv.w) + bb.w, 0.f);
    oB.x = fmaxf(diB * (aB.x + diB * hv.x) + bb.x, 0.f);
    oB.y = fmaxf(diB * (aB.y + diB * hv.y) + bb.y, 0.f);
    oB.z = fmaxf(diB * (aB.z + diB * hv.z) + bb.z, 0.f);
    oB.w = fmaxf(diB * (aB.w + diB * hv.w) + bb.w, 0.f);
    if (g == 0) {
        ((float4*)(x1H + (size_t)wid * 64))[sub] = oA;
        ((float4*)(x2H + (size_t)wid * 64))[sub] = oB;
    }
    float sA = oA.x * oA.x + oA.y * oA.y + oA.z * oA.z + oA.w * oA.w;
    float sB = oB.x * oB.x + oB.y * oB.y + oB.z * oB.z + oB.w * oB.w;
#pragma unroll
    for (int off = 8; off; off >>= 1) {
        sA += __shfl_xor(sA, off);
        sB += __shfl_xor(sB, off);
    }
    if (lane == 0) { sq1[wid] = sA; sq2[wid] = sB; }
}

// ---------------- layer-2 SpMM: 4-way parity (branch x half), bf16 h gathers ----------------
__global__ __launch_bounds__(256) void spmm2q_kernel(const unsigned short* __restrict__ h1A,
                                                     const unsigned short* __restrict__ h1B,
                                                     const unsigned short* __restrict__ h2A,
                                                     const unsigned short* __restrict__ h2B,
                                                     const float* __restrict__ wsA,
                                                     const float* __restrict__ wsB,
                                                     const unsigned short* __restrict__ col_s,
                                                     const float* __restrict__ disA,
                                                     const float* __restrict__ disB,
                                                     const int* __restrict__ row_ptr,
                                                     const float* __restrict__ bias,
                                                     float* __restrict__ x1A, float* __restrict__ x1B,
                                                     float* __restrict__ x2A, float* __restrict__ x2B,
                                                     int n) {
    int sel = blockIdx.x & 3;
    int br = sel & 1;      // 0 = cosine, 1 = euclid
    int half = sel >> 1;   // 0 = A, 1 = B
    const unsigned short* hH = br ? (half ? h2B : h2A) : (half ? h1B : h1A);
    const float* ws = br ? wsB : wsA;
    const float* dis = br ? disB : disA;
    float* outH = br ? (half ? x2B : x2A) : (half ? x1B : x1A);
    const float* biasH = bias + half * 64;
    int wid = (blockIdx.x >> 2) * 4 + (threadIdx.x >> 6);
    int lane = threadIdx.x & 63;
    if (wid >= n) return;
    int sub = lane & 15, g = lane >> 4;
    int s = row_ptr[wid], e = row_ptr[wid + 1];
    float di = dis[wid];
    float4 a = make_float4(0.f, 0.f, 0.f, 0.f);
    for (int base = s; base < e; base += 64) {
        int m = e - base; if (m > 64) m = 64;
        int cc = 0; float wv = 0.f;
        if (lane < m) {
            cc = (int)col_s[base + lane];
            wv = ws[base + lane] * dis[cc];
        }
#define SP2_BODY(CHK)                                                        \
        _Pragma("unroll")                                                    \
        for (int it = 0; it < 16; ++it) {                                    \
            int idx = it * 4 + g;                                            \
            int c = __shfl(cc, idx);                                         \
            float ce = __shfl(wv, idx);                                      \
            if (CHK) {                                                       \
                vus4 gv = ((const vus4*)(hH + (size_t)c * 64))[sub];         \
                a.x = fmaf(ce, bf2f(gv.x), a.x);                             \
                a.y = fmaf(ce, bf2f(gv.y), a.y);                             \
                a.z = fmaf(ce, bf2f(gv.z), a.z);                             \
                a.w = fmaf(ce, bf2f(gv.w), a.w);                             \
            }                                                                \
        }
        if (m == 64) { SP2_BODY(true) } else { SP2_BODY(idx < m) }
#undef SP2_BODY
    }
#pragma unroll
    for (int off = 16; off <= 32; off <<= 1) {
        a.x += __shfl_xor(a.x, off); a.y += __shfl_xor(a.y, off);
        a.z += __shfl_xor(a.z, off); a.w += __shfl_xor(a.w, off);
    }
    if (g == 0) {
        vus4 hvb = ((const vus4*)(hH + (size_t)wid * 64))[sub];
        float4 bb = ((const float4*)biasH)[sub];
        float4 o;
        o.x = di * (a.x + di * bf2f(hvb.x)) + bb.x;
        o.y = di * (a.y + di * bf2f(hvb.y)) + bb.y;
        o.z = di * (a.z + di * bf2f(hvb.z)) + bb.z;
        o.w = di * (a.w + di * bf2f(hvb.w)) + bb.w;
        ((float4*)(outH + (size_t)wid * 64))[sub] = o;
    }
}

// ---------------- semantic attention fusion ----------------
__global__ __launch_bounds__(256) void attn_kernel(const float* __restrict__ x1A,
                                                   const float* __restrict__ x1B,
                                                   const float* __restrict__ x2A,
                                                   const float* __restrict__ x2B,
                                                   const float* __restrict__ A1,
                                                   const float* __restrict__ ab1,
                                                   const float* __restrict__ A2,
                                                   float* __restrict__ out, int n) {
    __shared__ float sA1[DF * HATT];
    __shared__ float sA2[HATT];
    __shared__ float sab[HATT];
    int tid = threadIdx.x;
    for (int i = tid; i < DF * HATT; i += 256) sA1[i] = A1[i];
    if (tid < HATT) { sA2[tid] = A2[tid]; sab[tid] = ab1[tid]; }
    __syncthreads();
    int lane = tid & 63;
    int wib = tid >> 6;
    int wid = blockIdx.x * 4 + wib;
    int nw = gridDim.x * 4;
    for (int i = wid; i < n; i += nw) {
        float u0 = x1A[(size_t)i * 64 + lane], u1 = x1B[(size_t)i * 64 + lane];
        float v0 = x2A[(size_t)i * 64 + lane], v1 = x2B[(size_t)i * 64 + lane];
        float acc1 = 0.f, acc2 = 0.f;
#pragma unroll 4
        for (int d = 0; d < 64; ++d) {
            float w = sA1[d * HATT + lane];
            acc1 = fmaf(__shfl(u0, d), w, acc1);
            acc2 = fmaf(__shfl(v0, d), w, acc2);
        }
#pragma unroll 4
        for (int d = 0; d < 64; ++d) {
            float w = sA1[(d + 64) * HATT + lane];
            acc1 = fmaf(__shfl(u1, d), w, acc1);
            acc2 = fmaf(__shfl(v1, d), w, acc2);
        }
        float t1 = tanhf(acc1 + sab[lane]) * sA2[lane];
        float t2 = tanhf(acc2 + sab[lane]) * sA2[lane];
        for (int off = 32; off; off >>= 1) {
            t1 += __shfl_xor(t1, off);
            t2 += __shfl_xor(t2, off);
        }
        float mx = fmaxf(t1, t2);
        float e1 = expf(t1 - mx), e2 = expf(t2 - mx);
        float inv = 1.f / (e1 + e2);
        float be1 = e1 * inv, be2 = e2 * inv;
        out[(size_t)i * DF + lane] = be1 * u0 + be2 * v0;
        out[(size_t)i * DF + 64 + lane] = be1 * u1 + be2 * v1;
    }
}

// ---------------- launch ----------------

extern "C" void kernel_launch(void* const* d_in, const int* in_sizes, int n_in,
                              void* d_out, int out_size, void* d_ws, size_t ws_size,
                              hipStream_t stream) {
    const float* x  = (const float*)d_in[0];
    const int* row  = (const int*)d_in[1];
    const int* col  = (const int*)d_in[2];
    const float* W1 = (const float*)d_in[3];
    const float* b1 = (const float*)d_in[4];
    const float* W2 = (const float*)d_in[5];
    const float* b2 = (const float*)d_in[6];
    const float* A1 = (const float*)d_in[7];
    const float* ab1= (const float*)d_in[8];
    const float* A2 = (const float*)d_in[9];
    const int N = in_sizes[0] / DF;
    const int E = in_sizes[1];
    float* out = (float*)d_out;

    char* p = (char*)d_ws;
    auto alloc_b = [&](size_t bytes) -> char* {
        char* r = p;
        p += (bytes + 255) & ~(size_t)255;
        return r;
    };
    float* xA    = (float*)alloc_b((size_t)N * 64 * 4);
    float* xB    = (float*)alloc_b((size_t)N * 64 * 4);
    unsigned short* hA  = (unsigned short*)alloc_b((size_t)N * 64 * 2);  // bf16, also h1A
    unsigned short* hB  = (unsigned short*)alloc_b((size_t)N * 64 * 2);  // bf16, also h1B
    unsigned short* h2A = (unsigned short*)alloc_b((size_t)N * 64 * 2);
    unsigned short* h2B = (unsigned short*)alloc_b((size_t)N * 64 * 2);
    float* x1A   = (float*)alloc_b((size_t)N * 64 * 4);
    float* x1B   = (float*)alloc_b((size_t)N * 64 * 4);
    float* x2A   = (float*)alloc_b((size_t)N * 64 * 4);
    float* x2B   = (float*)alloc_b((size_t)N * 64 * 4);
    float* wsA   = (float*)alloc_b((size_t)E * 4);
    float* wsB   = (float*)alloc_b((size_t)E * 4);
    float* dp0   = (float*)alloc_b((size_t)E * 4);
    float* dp1   = (float*)alloc_b((size_t)E * 4);
    float* disA  = (float*)alloc_b((size_t)N * 4);
    float* disB  = (float*)alloc_b((size_t)N * 4);
    float* sqnx  = (float*)alloc_b((size_t)N * 4);
    float* sq1pA = (float*)alloc_b((size_t)N * 4);
    float* sq1pB = (float*)alloc_b((size_t)N * 4);
    float* sq2pA = (float*)alloc_b((size_t)N * 4);
    float* sq2pB = (float*)alloc_b((size_t)N * 4);
    int* cnt2    = (int*)alloc_b((size_t)SL * N * 4);
    int* tot     = (int*)alloc_b((size_t)N * 4);
    int* rowptr  = (int*)alloc_b((size_t)(N + 1) * 4);
    unsigned short* col_s = (unsigned short*)alloc_b((size_t)E * 2);
    (void)ws_size; (void)n_in; (void)out_size;

    const int nodeBlocks  = divup(N * 64, 256);   // 2500
    const int pairBlocks  = 2 * nodeBlocks;       // 5000
    const int quadBlocks  = 4 * nodeBlocks;       // 10000
    const int mmBlocks    = divup(divup(N, 4), 4);
    const int mm2Blocks   = 2 * mmBlocks;
    const int ranges = divup(N, RPB);
    const int rpb    = divup(N, ranges);
    int es = divup(E, SL); es = (es + 3) & ~3;
    const int prepBlocks = ranges * SL;

    // graph prep
    hist2_kernel<<<prepBlocks, 256, 0, stream>>>(row, cnt2, E, N, ranges, rpb, es);
    split_x_kernel<<<nodeBlocks, 256, 0, stream>>>(x, xA, xB, sqnx, N);
    scanRT_kernel<<<divup(N, 64), 256, 0, stream>>>(cnt2, tot, N);
    scanT_kernel<<<1, 1024, 0, stream>>>(tot, rowptr, N);
    scatter2_kernel<<<prepBlocks, 256, 0, stream>>>(row, col, cnt2, rowptr, col_s, E, N, ranges, rpb, es);

    // shared layer-1 transform -> bf16 h
    mm_kernel<<<mmBlocks, 256, 0, stream>>>(x, x + 64, DF, W1, hA, hB, N);

    // layer-1 edge weights (fp32 chain) + fused degrees
    edgewA_kernel<<<nodeBlocks, 256, 0, stream>>>(xA, col_s, rowptr, dp0, N);
    edgewB1_kernel<<<nodeBlocks, 256, 0, stream>>>(xB, sqnx, col_s, rowptr, dp0,
                                                   wsA, wsB, disA, disB, N);

    // layer-1 dual SpMM (bf16 h gathers), both halves in one launch
    spmm_l1_kernel<<<pairBlocks, 256, 0, stream>>>(hA, hB, wsA, wsB, col_s, disA, disB,
                                                   rowptr, b1, x1A, x1B, x2A, x2B,
                                                   sq1pA, sq1pB, sq2pA, sq2pB, N);

    // layer-2 edge weights, both branches paired (fp32 chain)
    edgewA2_kernel<<<pairBlocks, 256, 0, stream>>>(x1A, x2A, col_s, rowptr, dp0, dp1, N);
    edgewB2_kernel<<<pairBlocks, 256, 0, stream>>>(x1B, x2B, sq1pA, sq1pB, sq2pA, sq2pB,
                                                   col_s, rowptr, dp0, dp1,
                                                   wsA, wsB, disA, disB, N);

    // layer-2 transforms, both branches paired -> bf16 h
    mm2_kernel<<<mm2Blocks, 256, 0, stream>>>(x1A, x1B, x2A, x2B, W2, hA, hB, h2A, h2B, N);

    // layer-2 SpMM: single 4-way launch (branch x half), bf16 h gathers
    spmm2q_kernel<<<quadBlocks, 256, 0, stream>>>(hA, hB, h2A, h2B, wsA, wsB, col_s,
                                                  disA, disB, rowptr, b2,
                                                  x1A, x1B, x2A, x2B, N);

    // semantic attention fusion -> out
    attn_kernel<<<divup(N, 4), 256, 0, stream>>>(x1A, x1B, x2A, x2B, A1, ab1, A2, out, N);
}

// Round 14
// 349.430 us; speedup vs baseline: 1.1781x; 1.0210x over previous
//
#include <hip/hip_runtime.h>
#include <cstdint>
#include <cstddef>

#define DF 128      // feature dim
#define HATT 64     // attention hidden dim
#define SL 64       // edge slices for graph prep
#define RPB 1280    // max rows per range-block (LDS counters)

static inline int divup(int a, int b) { return (a + b - 1) / b; }

typedef int vint4 __attribute__((ext_vector_type(4)));              // nontemporal-compatible
typedef unsigned short vus4 __attribute__((ext_vector_type(4)));    // bf16x4 gather

// bf16 round-to-nearest-even (values only used in LINEAR aggregation; the
// weight->deg->rsqrt chain stays fp32 -- bf16 there was catastrophic, round 2)
static __device__ __forceinline__ unsigned short f2bf(float f) {
    unsigned int u = __float_as_uint(f);
    u = (u + 0x7FFFu + ((u >> 16) & 1u)) >> 16;
    return (unsigned short)u;
}
static __device__ __forceinline__ float bf2f(unsigned short b) {
    return __uint_as_float(((unsigned int)b) << 16);
}

// ---------------- graph prep ----------------
__global__ __launch_bounds__(256) void hist2_kernel(const int* __restrict__ row,
                                                    int* __restrict__ cnt2,
                                                    int E, int n, int ranges, int rpb, int es) {
    int rb = blockIdx.x % ranges;
    int s  = blockIdx.x / ranges;
    int lo = rb * rpb, hi = min(lo + rpb, n);
    int rows = hi - lo;
    __shared__ int lc[RPB];
    for (int j = threadIdx.x; j < rows; j += 256) lc[j] = 0;
    __syncthreads();
    int i0 = s * es, i1 = min(i0 + es, E);
    const vint4* rv = (const vint4*)row;
    for (int j = i0 / 4 + threadIdx.x; j < i1 / 4; j += 256) {
        vint4 r4 = __builtin_nontemporal_load(rv + j);
        if (r4.x >= lo && r4.x < hi) atomicAdd(&lc[r4.x - lo], 1);
        if (r4.y >= lo && r4.y < hi) atomicAdd(&lc[r4.y - lo], 1);
        if (r4.z >= lo && r4.z < hi) atomicAdd(&lc[r4.z - lo], 1);
        if (r4.w >= lo && r4.w < hi) atomicAdd(&lc[r4.w - lo], 1);
    }
    __syncthreads();
    for (int j = threadIdx.x; j < rows; j += 256) cnt2[(size_t)s * n + lo + j] = lc[j];
}

__global__ __launch_bounds__(256) void scanRT_kernel(int* __restrict__ cnt2,
                                                     int* __restrict__ tot, int n) {
    __shared__ int tile[SL][65];
    int r0 = blockIdx.x * 64;
    int w = threadIdx.x >> 6;
    int lane = threadIdx.x & 63;
    int rows = min(64, n - r0);
    for (int s = w; s < SL; s += 4) {
        int v = (lane < rows) ? cnt2[(size_t)s * n + r0 + lane] : 0;
        tile[s][lane] = v;
    }
    __syncthreads();
    int t = threadIdx.x;
    if (t < rows) {
        int run = 0;
#pragma unroll
        for (int s = 0; s < SL; ++s) {
            int v = tile[s][t];
            tile[s][t] = run;
            run += v;
        }
        tot[r0 + t] = run;
    }
    __syncthreads();
    for (int s = w; s < SL; s += 4) {
        if (lane < rows) cnt2[(size_t)s * n + r0 + lane] = tile[s][lane];
    }
}

__global__ __launch_bounds__(1024) void scanT_kernel(const int* __restrict__ tot,
                                                     int* __restrict__ row_ptr, int n) {
    __shared__ int sums[1024];
    int t = threadIdx.x;
    int chunk = (n + 1023) >> 10;
    int start = t * chunk, end = min(start + chunk, n);
    int s = 0;
    for (int r = start; r < end; ++r) s += tot[r];
    sums[t] = s;
    __syncthreads();
    for (int off = 1; off < 1024; off <<= 1) {
        int v = (t >= off) ? sums[t - off] : 0;
        __syncthreads();
        sums[t] += v;
        __syncthreads();
    }
    int run = sums[t] - s;
    for (int r = start; r < end; ++r) {
        row_ptr[r] = run;
        run += tot[r];
    }
    if (t == 1023) row_ptr[n] = sums[1023];
}

__global__ __launch_bounds__(256) void scatter2_kernel(const int* __restrict__ row,
                                                       const int* __restrict__ col,
                                                       const int* __restrict__ cnt2,
                                                       const int* __restrict__ row_ptr,
                                                       unsigned short* __restrict__ col_s,
                                                       int E, int n, int ranges, int rpb, int es) {
    int rb = blockIdx.x % ranges;
    int s  = blockIdx.x / ranges;
    int lo = rb * rpb, hi = min(lo + rpb, n);
    int rows = hi - lo;
    __shared__ int cur[RPB];
    for (int j = threadIdx.x; j < rows; j += 256)
        cur[j] = cnt2[(size_t)s * n + lo + j] + row_ptr[lo + j];
    __syncthreads();
    int i0 = s * es, i1 = min(i0 + es, E);
    const vint4* rv = (const vint4*)row;
    const vint4* cv = (const vint4*)col;
    for (int j = i0 / 4 + threadIdx.x; j < i1 / 4; j += 256) {
        vint4 r4 = __builtin_nontemporal_load(rv + j);
        bool b0 = (r4.x >= lo && r4.x < hi);
        bool b1 = (r4.y >= lo && r4.y < hi);
        bool b2 = (r4.z >= lo && r4.z < hi);
        bool b3 = (r4.w >= lo && r4.w < hi);
        if (b0 | b1 | b2 | b3) {
            vint4 c4 = __builtin_nontemporal_load(cv + j);
            if (b0) { int p = atomicAdd(&cur[r4.x - lo], 1); col_s[p] = (unsigned short)c4.x; }
            if (b1) { int p = atomicAdd(&cur[r4.y - lo], 1); col_s[p] = (unsigned short)c4.y; }
            if (b2) { int p = atomicAdd(&cur[r4.z - lo], 1); col_s[p] = (unsigned short)c4.z; }
            if (b3) { int p = atomicAdd(&cur[r4.w - lo], 1); col_s[p] = (unsigned short)c4.w; }
        }
    }
}

// ---------------- split x + squared norms ----------------
__global__ __launch_bounds__(256) void split_x_kernel(const float* __restrict__ x,
                                                      float* __restrict__ xA,
                                                      float* __restrict__ xB,
                                                      float* __restrict__ sqn, int n) {
    int wid = (blockIdx.x * blockDim.x + threadIdx.x) >> 6;
    int lane = threadIdx.x & 63;
    if (wid >= n) return;
    float v0 = x[(size_t)wid * DF + lane];
    float v1 = x[(size_t)wid * DF + 64 + lane];
    xA[(size_t)wid * 64 + lane] = v0;
    xB[(size_t)wid * 64 + lane] = v1;
    float s = v0 * v0 + v1 * v1;
    for (int off = 32; off; off >>= 1) s += __shfl_xor(s, off);
    if (lane == 0) sqn[wid] = s;
}

// ---------------- edge weights (fp32 tables, branchless keep) ----------------
__global__ __launch_bounds__(256) void edgewA_kernel(const float* __restrict__ tA,
                                                     const unsigned short* __restrict__ col_s,
                                                     const int* __restrict__ row_ptr,
                                                     float* __restrict__ dpart, int n) {
    int wid = (blockIdx.x * blockDim.x + threadIdx.x) >> 6;
    int lane = threadIdx.x & 63;
    if (wid >= n) return;
    int sub = lane & 15, g = lane >> 4;
    int s = row_ptr[wid], e = row_ptr[wid + 1];
    float4 a = ((const float4*)(tA + (size_t)wid * 64))[sub];
    for (int base = s; base < e; base += 64) {
        int m = e - base; if (m > 64) m = 64;
        int cc = 0;
        if (lane < m) cc = (int)col_s[base + lane];
        float dkeep = 0.f;
#define EWA_BODY(CHK)                                                        \
        _Pragma("unroll")                                                    \
        for (int it = 0; it < 16; ++it) {                                    \
            int idx = g * 16 + it;                                           \
            int c = __shfl(cc, idx);                                         \
            if (CHK) {                                                       \
                float4 b = ((const float4*)(tA + (size_t)c * 64))[sub];      \
                float d = a.x * b.x + a.y * b.y + a.z * b.z + a.w * b.w;     \
                d += __shfl_xor(d, 8); d += __shfl_xor(d, 4);                \
                d += __shfl_xor(d, 2); d += __shfl_xor(d, 1);                \
                dkeep = (sub == it) ? d : dkeep;                             \
            }                                                                \
        }
        if (m == 64) { EWA_BODY(true) } else { EWA_BODY(idx < m) }
#undef EWA_BODY
        if (lane < m) dpart[base + lane] = dkeep;
    }
}

__global__ __launch_bounds__(256) void edgewB1_kernel(const float* __restrict__ tB,
                                                      const float* __restrict__ sqn,
                                                      const unsigned short* __restrict__ col_s,
                                                      const int* __restrict__ row_ptr,
                                                      const float* __restrict__ dpart,
                                                      float* __restrict__ wA,
                                                      float* __restrict__ wB,
                                                      float* __restrict__ disA,
                                                      float* __restrict__ disB, int n) {
    int wid = (blockIdx.x * blockDim.x + threadIdx.x) >> 6;
    int lane = threadIdx.x & 63;
    if (wid >= n) return;
    int sub = lane & 15, g = lane >> 4;
    int s = row_ptr[wid], e = row_ptr[wid + 1];
    float4 a = ((const float4*)(tB + (size_t)wid * 64))[sub];
    float na = sqn[wid];
    float accA = 0.f, accB = 0.f;
    for (int base = s; base < e; base += 64) {
        int m = e - base; if (m > 64) m = 64;
        int cc = 0; float dp = 0.f;
        if (lane < m) {
            cc = (int)col_s[base + lane];
            dp = dpart[base + lane];
        }
        float dkeep = 0.f;
#define EWB1_BODY(CHK)                                                       \
        _Pragma("unroll")                                                    \
        for (int it = 0; it < 16; ++it) {                                    \
            int idx = g * 16 + it;                                           \
            int c = __shfl(cc, idx);                                         \
            if (CHK) {                                                       \
                float4 b = ((const float4*)(tB + (size_t)c * 64))[sub];      \
                float d = a.x * b.x + a.y * b.y + a.z * b.z + a.w * b.w;     \
                d += __shfl_xor(d, 8); d += __shfl_xor(d, 4);                \
                d += __shfl_xor(d, 2); d += __shfl_xor(d, 1);                \
                dkeep = (sub == it) ? d : dkeep;                             \
            }                                                                \
        }
        if (m == 64) { EWB1_BODY(true) } else { EWB1_BODY(idx < m) }
#undef EWB1_BODY
        if (lane < m) {
            float d = dkeep + dp;
            float nb = sqn[cc];
            float cw = d / fmaxf(sqrtf(na * nb), 1e-8f);
            float ew = sqrtf(fmaxf(na + nb - 2.f * d, 0.f) + 1e-12f);
            wA[base + lane] = cw;
            wB[base + lane] = ew;
            accA += cw;
            accB += ew;
        }
    }
#pragma unroll
    for (int off = 32; off; off >>= 1) {
        accA += __shfl_xor(accA, off);
        accB += __shfl_xor(accB, off);
    }
    if (lane == 0) {
        float dA = 1.f + accA;
        disA[wid] = (dA > 0.f) ? rsqrtf(fmaxf(dA, 1e-12f)) : 0.f;
        float dB = 1.f + accB;
        disB[wid] = (dB > 0.f) ? rsqrtf(fmaxf(dB, 1e-12f)) : 0.f;
    }
}

__global__ __launch_bounds__(256) void edgewA2_kernel(const float* __restrict__ t0,
                                                      const float* __restrict__ t1,
                                                      const unsigned short* __restrict__ col_s,
                                                      const int* __restrict__ row_ptr,
                                                      float* __restrict__ dp0,
                                                      float* __restrict__ dp1, int n) {
    int br = blockIdx.x & 1;
    int wid = (blockIdx.x >> 1) * 4 + (threadIdx.x >> 6);
    int lane = threadIdx.x & 63;
    if (wid >= n) return;
    const float* tA = br ? t1 : t0;
    float* dpart = br ? dp1 : dp0;
    int sub = lane & 15, g = lane >> 4;
    int s = row_ptr[wid], e = row_ptr[wid + 1];
    float4 a = ((const float4*)(tA + (size_t)wid * 64))[sub];
    for (int base = s; base < e; base += 64) {
        int m = e - base; if (m > 64) m = 64;
        int cc = 0;
        if (lane < m) cc = (int)col_s[base + lane];
        float dkeep = 0.f;
#define EWA2_BODY(CHK)                                                       \
        _Pragma("unroll")                                                    \
        for (int it = 0; it < 16; ++it) {                                    \
            int idx = g * 16 + it;                                           \
            int c = __shfl(cc, idx);                                         \
            if (CHK) {                                                       \
                float4 b = ((const float4*)(tA + (size_t)c * 64))[sub];      \
                float d = a.x * b.x + a.y * b.y + a.z * b.z + a.w * b.w;     \
                d += __shfl_xor(d, 8); d += __shfl_xor(d, 4);                \
                d += __shfl_xor(d, 2); d += __shfl_xor(d, 1);                \
                dkeep = (sub == it) ? d : dkeep;                             \
            }                                                                \
        }
        if (m == 64) { EWA2_BODY(true) } else { EWA2_BODY(idx < m) }
#undef EWA2_BODY
        if (lane < m) dpart[base + lane] = dkeep;
    }
}

__global__ __launch_bounds__(256) void edgewB2_kernel(const float* __restrict__ t0B,
                                                      const float* __restrict__ t1B,
                                                      const float* __restrict__ sqn1,
                                                      const float* __restrict__ sqn2,
                                                      const unsigned short* __restrict__ col_s,
                                                      const int* __restrict__ row_ptr,
                                                      const float* __restrict__ dp0,
                                                      const float* __restrict__ dp1,
                                                      float* __restrict__ wsA,
                                                      float* __restrict__ wsB,
                                                      float* __restrict__ disA,
                                                      float* __restrict__ disB, int n) {
    int br = blockIdx.x & 1;
    int wid = (blockIdx.x >> 1) * 4 + (threadIdx.x >> 6);
    int lane = threadIdx.x & 63;
    if (wid >= n) return;
    const float* tB = br ? t1B : t0B;
    const float* sq = br ? sqn2 : sqn1;
    const float* dpart = br ? dp1 : dp0;
    float* wOut = br ? wsB : wsA;
    float* disOut = br ? disB : disA;
    int sub = lane & 15, g = lane >> 4;
    int s = row_ptr[wid], e = row_ptr[wid + 1];
    float4 a = ((const float4*)(tB + (size_t)wid * 64))[sub];
    float na = sq[wid];
    float acc = 0.f;
    for (int base = s; base < e; base += 64) {
        int m = e - base; if (m > 64) m = 64;
        int cc = 0; float dp = 0.f;
        if (lane < m) {
            cc = (int)col_s[base + lane];
            dp = dpart[base + lane];
        }
        float dkeep = 0.f;
#define EWB2_BODY(CHK)                                                       \
        _Pragma("unroll")                                                    \
        for (int it = 0; it < 16; ++it) {                                    \
            int idx = g * 16 + it;                                           \
            int c = __shfl(cc, idx);                                         \
            if (CHK) {                                                       \
                float4 b = ((const float4*)(tB + (size_t)c * 64))[sub];      \
                float d = a.x * b.x + a.y * b.y + a.z * b.z + a.w * b.w;     \
                d += __shfl_xor(d, 8); d += __shfl_xor(d, 4);                \
                d += __shfl_xor(d, 2); d += __shfl_xor(d, 1);                \
                dkeep = (sub == it) ? d : dkeep;                             \
            }                                                                \
        }
        if (m == 64) { EWB2_BODY(true) } else { EWB2_BODY(idx < m) }
#undef EWB2_BODY
        if (lane < m) {
            float d = dkeep + dp;
            float nb = sq[cc];
            float w;
            if (br == 0) w = d / fmaxf(sqrtf(na * nb), 1e-8f);
            else w = sqrtf(fmaxf(na + nb - 2.f * d, 0.f) + 1e-12f);
            wOut[base + lane] = w;
            acc += w;
        }
    }
#pragma unroll
    for (int off = 32; off; off >>= 1) acc += __shfl_xor(acc, off);
    if (lane == 0) {
        float dg = 1.f + acc;
        disOut[wid] = (dg > 0.f) ? rsqrtf(fmaxf(dg, 1e-12f)) : 0.f;
    }
}

// ---------------- dense matmuls -> bf16 h tables ----------------
__global__ __launch_bounds__(256) void mm_kernel(const float* __restrict__ inA,
                                                 const float* __restrict__ inB,
                                                 int strideIn,
                                                 const float* __restrict__ W,
                                                 unsigned short* __restrict__ hA,
                                                 unsigned short* __restrict__ hB, int n) {
    int wid = (blockIdx.x * blockDim.x + threadIdx.x) >> 6;
    int lane = threadIdx.x & 63;
    int i0 = wid * 4;
    if (i0 >= n) return;
    float v0[4], v1[4];
#pragma unroll
    for (int r = 0; r < 4; ++r) {
        int i = i0 + r;
        if (i < n) { v0[r] = inA[(size_t)i * strideIn + lane]; v1[r] = inB[(size_t)i * strideIn + lane]; }
        else { v0[r] = 0.f; v1[r] = 0.f; }
    }
    float acc0[4] = {0.f, 0.f, 0.f, 0.f};
    float acc1[4] = {0.f, 0.f, 0.f, 0.f};
#pragma unroll 4
    for (int k = 0; k < 64; ++k) {
        float w0 = W[k * DF + lane];
        float w1 = W[k * DF + 64 + lane];
#pragma unroll
        for (int r = 0; r < 4; ++r) {
            float a = __shfl(v0[r], k);
            acc0[r] = fmaf(a, w0, acc0[r]);
            acc1[r] = fmaf(a, w1, acc1[r]);
        }
    }
#pragma unroll 4
    for (int k = 0; k < 64; ++k) {
        float w0 = W[(k + 64) * DF + lane];
        float w1 = W[(k + 64) * DF + 64 + lane];
#pragma unroll
        for (int r = 0; r < 4; ++r) {
            float a = __shfl(v1[r], k);
            acc0[r] = fmaf(a, w0, acc0[r]);
            acc1[r] = fmaf(a, w1, acc1[r]);
        }
    }
#pragma unroll
    for (int r = 0; r < 4; ++r) {
        int i = i0 + r;
        if (i < n) {
            hA[(size_t)i * 64 + lane] = f2bf(acc0[r]);
            hB[(size_t)i * 64 + lane] = f2bf(acc1[r]);
        }
    }
}

// paired layer-2 mm: branch parity
__global__ __launch_bounds__(256) void mm2_kernel(const float* __restrict__ x1A_,
                                                  const float* __restrict__ x1B_,
                                                  const float* __restrict__ x2A_,
                                                  const float* __restrict__ x2B_,
                                                  const float* __restrict__ W,
                                                  unsigned short* __restrict__ h1A, unsigned short* __restrict__ h1B,
                                                  unsigned short* __restrict__ h2A, unsigned short* __restrict__ h2B,
                                                  int n) {
    int br = blockIdx.x & 1;
    const float* inA = br ? x2A_ : x1A_;
    const float* inB = br ? x2B_ : x1B_;
    unsigned short* hA = br ? h2A : h1A;
    unsigned short* hB = br ? h2B : h1B;
    int wid = (blockIdx.x >> 1) * 4 + (threadIdx.x >> 6);
    int lane = threadIdx.x & 63;
    int i0 = wid * 4;
    if (i0 >= n) return;
    float v0[4], v1[4];
#pragma unroll
    for (int r = 0; r < 4; ++r) {
        int i = i0 + r;
        if (i < n) { v0[r] = inA[(size_t)i * 64 + lane]; v1[r] = inB[(size_t)i * 64 + lane]; }
        else { v0[r] = 0.f; v1[r] = 0.f; }
    }
    float acc0[4] = {0.f, 0.f, 0.f, 0.f};
    float acc1[4] = {0.f, 0.f, 0.f, 0.f};
#pragma unroll 4
    for (int k = 0; k < 64; ++k) {
        float w0 = W[k * DF + lane];
        float w1 = W[k * DF + 64 + lane];
#pragma unroll
        for (int r = 0; r < 4; ++r) {
            float a = __shfl(v0[r], k);
            acc0[r] = fmaf(a, w0, acc0[r]);
            acc1[r] = fmaf(a, w1, acc1[r]);
        }
    }
#pragma unroll 4
    for (int k = 0; k < 64; ++k) {
        float w0 = W[(k + 64) * DF + lane];
        float w1 = W[(k + 64) * DF + 64 + lane];
#pragma unroll
        for (int r = 0; r < 4; ++r) {
            float a = __shfl(v1[r], k);
            acc0[r] = fmaf(a, w0, acc0[r]);
            acc1[r] = fmaf(a, w1, acc1[r]);
        }
    }
#pragma unroll
    for (int r = 0; r < 4; ++r) {
        int i = i0 + r;
        if (i < n) {
            hA[(size_t)i * 64 + lane] = f2bf(acc0[r]);
            hB[(size_t)i * 64 + lane] = f2bf(acc1[r]);
        }
    }
}

// ---------------- layer-1 dual SpMM: one wave per node, BOTH halves + BOTH branches ----------------
// bf16 hA+hB working set = 2.56 MB (L2-resident). 32 loads in flight per chunk.
__global__ __launch_bounds__(256) void spmm_l1_kernel(const unsigned short* __restrict__ hA,
                                                      const unsigned short* __restrict__ hB,
                                                      const float* __restrict__ wsA,
                                                      const float* __restrict__ wsB,
                                                      const unsigned short* __restrict__ col_s,
                                                      const float* __restrict__ disA,
                                                      const float* __restrict__ disB,
                                                      const int* __restrict__ row_ptr,
                                                      const float* __restrict__ bias,
                                                      float* __restrict__ x1A, float* __restrict__ x1B,
                                                      float* __restrict__ x2A, float* __restrict__ x2B,
                                                      float* __restrict__ sqn1, float* __restrict__ sqn2,
                                                      int n) {
    int wid = (blockIdx.x * blockDim.x + threadIdx.x) >> 6;
    int lane = threadIdx.x & 63;
    if (wid >= n) return;
    int sub = lane & 15, g = lane >> 4;
    int s = row_ptr[wid], e = row_ptr[wid + 1];
    float diA = disA[wid], diB = disB[wid];
    float4 a1A = make_float4(0.f, 0.f, 0.f, 0.f);  // branch cos, half A
    float4 a1B = make_float4(0.f, 0.f, 0.f, 0.f);  // branch cos, half B
    float4 a2A = make_float4(0.f, 0.f, 0.f, 0.f);  // branch euc, half A
    float4 a2B = make_float4(0.f, 0.f, 0.f, 0.f);  // branch euc, half B
    for (int base = s; base < e; base += 64) {
        int m = e - base; if (m > 64) m = 64;
        int cc = 0; float wa = 0.f, wb = 0.f;
        if (lane < m) {
            cc = (int)col_s[base + lane];
            wa = wsA[base + lane] * disA[cc];
            wb = wsB[base + lane] * disB[cc];
        }
#define SPL1_BODY(CHK)                                                       \
        _Pragma("unroll")                                                    \
        for (int it = 0; it < 16; ++it) {                                    \
            int idx = it * 4 + g;                                            \
            int c = __shfl(cc, idx);                                         \
            float ceA = __shfl(wa, idx);                                     \
            float ceB = __shfl(wb, idx);                                     \
            if (CHK) {                                                       \
                vus4 gA = ((const vus4*)(hA + (size_t)c * 64))[sub];         \
                vus4 gB = ((const vus4*)(hB + (size_t)c * 64))[sub];         \
                float fa0 = bf2f(gA.x), fa1 = bf2f(gA.y);                    \
                float fa2 = bf2f(gA.z), fa3 = bf2f(gA.w);                    \
                float fb0 = bf2f(gB.x), fb1 = bf2f(gB.y);                    \
                float fb2 = bf2f(gB.z), fb3 = bf2f(gB.w);                    \
                a1A.x = fmaf(ceA, fa0, a1A.x); a1A.y = fmaf(ceA, fa1, a1A.y);\
                a1A.z = fmaf(ceA, fa2, a1A.z); a1A.w = fmaf(ceA, fa3, a1A.w);\
                a1B.x = fmaf(ceA, fb0, a1B.x); a1B.y = fmaf(ceA, fb1, a1B.y);\
                a1B.z = fmaf(ceA, fb2, a1B.z); a1B.w = fmaf(ceA, fb3, a1B.w);\
                a2A.x = fmaf(ceB, fa0, a2A.x); a2A.y = fmaf(ceB, fa1, a2A.y);\
                a2A.z = fmaf(ceB, fa2, a2A.z); a2A.w = fmaf(ceB, fa3, a2A.w);\
                a2B.x = fmaf(ceB, fb0, a2B.x); a2B.y = fmaf(ceB, fb1, a2B.y);\
                a2B.z = fmaf(ceB, fb2, a2B.z); a2B.w = fmaf(ceB, fb3, a2B.w);\
            }                                                                \
        }
        if (m == 64) { SPL1_BODY(true) } else { SPL1_BODY(idx < m) }
#undef SPL1_BODY
    }
#pragma unroll
    for (int off = 16; off <= 32; off <<= 1) {
        a1A.x += __shfl_xor(a1A.x, off); a1A.y += __shfl_xor(a1A.y, off);
        a1A.z += __shfl_xor(a1A.z, off); a1A.w += __shfl_xor(a1A.w, off);
        a1B.x += __shfl_xor(a1B.x, off); a1B.y += __shfl_xor(a1B.y, off);
        a1B.z += __shfl_xor(a1B.z, off); a1B.w += __shfl_xor(a1B.w, off);
        a2A.x += __shfl_xor(a2A.x, off); a2A.y += __shfl_xor(a2A.y, off);
        a2A.z += __shfl_xor(a2A.z, off); a2A.w += __shfl_xor(a2A.w, off);
        a2B.x += __shfl_xor(a2B.x, off); a2B.y += __shfl_xor(a2B.y, off);
        a2B.z += __shfl_xor(a2B.z, off); a2B.w += __shfl_xor(a2B.w, off);
    }
    vus4 hvAb = ((const vus4*)(hA + (size_t)wid * 64))[sub];
    vus4 hvBb = ((const vus4*)(hB + (size_t)wid * 64))[sub];
    float4 hvA = make_float4(bf2f(hvAb.x), bf2f(hvAb.y), bf2f(hvAb.z), bf2f(hvAb.w));
    float4 hvB = make_float4(bf2f(hvBb.x), bf2f(hvBb.y), bf2f(hvBb.z), bf2f(hvBb.w));
    float4 bbA = ((const float4*)bias)[sub];
    float4 bbB = ((const float4*)(bias + 64))[sub];
    float4 o1A, o1B, o2A, o2B;
    o1A.x = fmaxf(diA * (a1A.x + diA * hvA.x) + bbA.x, 0.f);
    o1A.y = fmaxf(diA * (a1A.y + diA * hvA.y) + bbA.y, 0.f);
    o1A.z = fmaxf(diA * (a1A.z + diA * hvA.z) + bbA.z, 0.f);
    o1A.w = fmaxf(diA * (a1A.w + diA * hvA.w) + bbA.w, 0.f);
    o1B.x = fmaxf(diA * (a1B.x + diA * hvB.x) + bbB.x, 0.f);
    o1B.y = fmaxf(diA * (a1B.y + diA * hvB.y) + bbB.y, 0.f);
    o1B.z = fmaxf(diA * (a1B.z + diA * hvB.z) + bbB.z, 0.f);
    o1B.w = fmaxf(diA * (a1B.w + diA * hvB.w) + bbB.w, 0.f);
    o2A.x = fmaxf(diB * (a2A.x + diB * hvA.x) + bbA.x, 0.f);
    o2A.y = fmaxf(diB * (a2A.y + diB * hvA.y) + bbA.y, 0.f);
    o2A.z = fmaxf(diB * (a2A.z + diB * hvA.z) + bbA.z, 0.f);
    o2A.w = fmaxf(diB * (a2A.w + diB * hvA.w) + bbA.w, 0.f);
    o2B.x = fmaxf(diB * (a2B.x + diB * hvB.x) + bbB.x, 0.f);
    o2B.y = fmaxf(diB * (a2B.y + diB * hvB.y) + bbB.y, 0.f);
    o2B.z = fmaxf(diB * (a2B.z + diB * hvB.z) + bbB.z, 0.f);
    o2B.w = fmaxf(diB * (a2B.w + diB * hvB.w) + bbB.w, 0.f);
    if (g == 0) {
        ((float4*)(x1A + (size_t)wid * 64))[sub] = o1A;
        ((float4*)(x1B + (size_t)wid * 64))[sub] = o1B;
        ((float4*)(x2A + (size_t)wid * 64))[sub] = o2A;
        ((float4*)(x2B + (size_t)wid * 64))[sub] = o2B;
    }
    float s1 = o1A.x * o1A.x + o1A.y * o1A.y + o1A.z * o1A.z + o1A.w * o1A.w
             + o1B.x * o1B.x + o1B.y * o1B.y + o1B.z * o1B.z + o1B.w * o1B.w;
    float s2 = o2A.x * o2A.x + o2A.y * o2A.y + o2A.z * o2A.z + o2A.w * o2A.w
             + o2B.x * o2B.x + o2B.y * o2B.y + o2B.z * o2B.z + o2B.w * o2B.w;
#pragma unroll
    for (int off = 8; off; off >>= 1) {
        s1 += __shfl_xor(s1, off);
        s2 += __shfl_xor(s2, off);
    }
    if (lane == 0) { sqn1[wid] = s1; sqn2[wid] = s2; }
}

// ---------------- layer-2 SpMM: branch parity only, BOTH halves per wave ----------------
__global__ __launch_bounds__(256) void spmm2d_kernel(const unsigned short* __restrict__ h1A,
                                                     const unsigned short* __restrict__ h1B,
                                                     const unsigned short* __restrict__ h2A,
                                                     const unsigned short* __restrict__ h2B,
                                                     const float* __restrict__ wsA,
                                                     const float* __restrict__ wsB,
                                                     const unsigned short* __restrict__ col_s,
                                                     const float* __restrict__ disA,
                                                     const float* __restrict__ disB,
                                                     const int* __restrict__ row_ptr,
                                                     const float* __restrict__ bias,
                                                     float* __restrict__ x1A, float* __restrict__ x1B,
                                                     float* __restrict__ x2A, float* __restrict__ x2B,
                                                     int n) {
    int br = blockIdx.x & 1;   // 0 = cosine, 1 = euclid
    const unsigned short* hHA = br ? h2A : h1A;
    const unsigned short* hHB = br ? h2B : h1B;
    const float* ws = br ? wsB : wsA;
    const float* dis = br ? disB : disA;
    float* outA = br ? x2A : x1A;
    float* outB = br ? x2B : x1B;
    int wid = (blockIdx.x >> 1) * 4 + (threadIdx.x >> 6);
    int lane = threadIdx.x & 63;
    if (wid >= n) return;
    int sub = lane & 15, g = lane >> 4;
    int s = row_ptr[wid], e = row_ptr[wid + 1];
    float di = dis[wid];
    float4 aA = make_float4(0.f, 0.f, 0.f, 0.f);
    float4 aB = make_float4(0.f, 0.f, 0.f, 0.f);
    for (int base = s; base < e; base += 64) {
        int m = e - base; if (m > 64) m = 64;
        int cc = 0; float wv = 0.f;
        if (lane < m) {
            cc = (int)col_s[base + lane];
            wv = ws[base + lane] * dis[cc];
        }
#define SP2_BODY(CHK)                                                        \
        _Pragma("unroll")                                                    \
        for (int it = 0; it < 16; ++it) {                                    \
            int idx = it * 4 + g;                                            \
            int c = __shfl(cc, idx);                                         \
            float ce = __shfl(wv, idx);                                      \
            if (CHK) {                                                       \
                vus4 gA = ((const vus4*)(hHA + (size_t)c * 64))[sub];        \
                vus4 gB = ((const vus4*)(hHB + (size_t)c * 64))[sub];        \
                aA.x = fmaf(ce, bf2f(gA.x), aA.x);                           \
                aA.y = fmaf(ce, bf2f(gA.y), aA.y);                           \
                aA.z = fmaf(ce, bf2f(gA.z), aA.z);                           \
                aA.w = fmaf(ce, bf2f(gA.w), aA.w);                           \
                aB.x = fmaf(ce, bf2f(gB.x), aB.x);                           \
                aB.y = fmaf(ce, bf2f(gB.y), aB.y);                           \
                aB.z = fmaf(ce, bf2f(gB.z), aB.z);                           \
                aB.w = fmaf(ce, bf2f(gB.w), aB.w);                           \
            }                                                                \
        }
        if (m == 64) { SP2_BODY(true) } else { SP2_BODY(idx < m) }
#undef SP2_BODY
    }
#pragma unroll
    for (int off = 16; off <= 32; off <<= 1) {
        aA.x += __shfl_xor(aA.x, off); aA.y += __shfl_xor(aA.y, off);
        aA.z += __shfl_xor(aA.z, off); aA.w += __shfl_xor(aA.w, off);
        aB.x += __shfl_xor(aB.x, off); aB.y += __shfl_xor(aB.y, off);
        aB.z += __shfl_xor(aB.z, off); aB.w += __shfl_xor(aB.w, off);
    }
    if (g == 0) {
        vus4 hvAb = ((const vus4*)(hHA + (size_t)wid * 64))[sub];
        vus4 hvBb = ((const vus4*)(hHB + (size_t)wid * 64))[sub];
        float4 bbA = ((const float4*)bias)[sub];
        float4 bbB = ((const float4*)(bias + 64))[sub];
        float4 oA, oB;
        oA.x = di * (aA.x + di * bf2f(hvAb.x)) + bbA.x;
        oA.y = di * (aA.y + di * bf2f(hvAb.y)) + bbA.y;
        oA.z = di * (aA.z + di * bf2f(hvAb.z)) + bbA.z;
        oA.w = di * (aA.w + di * bf2f(hvAb.w)) + bbA.w;
        oB.x = di * (aB.x + di * bf2f(hvBb.x)) + bbB.x;
        oB.y = di * (aB.y + di * bf2f(hvBb.y)) + bbB.y;
        oB.z = di * (aB.z + di * bf2f(hvBb.z)) + bbB.z;
        oB.w = di * (aB.w + di * bf2f(hvBb.w)) + bbB.w;
        ((float4*)(outA + (size_t)wid * 64))[sub] = oA;
        ((float4*)(outB + (size_t)wid * 64))[sub] = oB;
    }
}

// ---------------- semantic attention fusion ----------------
__global__ __launch_bounds__(256) void attn_kernel(const float* __restrict__ x1A,
                                                   const float* __restrict__ x1B,
                                                   const float* __restrict__ x2A,
                                                   const float* __restrict__ x2B,
                                                   const float* __restrict__ A1,
                                                   const float* __restrict__ ab1,
                                                   const float* __restrict__ A2,
                                                   float* __restrict__ out, int n) {
    __shared__ float sA1[DF * HATT];
    __shared__ float sA2[HATT];
    __shared__ float sab[HATT];
    int tid = threadIdx.x;
    for (int i = tid; i < DF * HATT; i += 256) sA1[i] = A1[i];
    if (tid < HATT) { sA2[tid] = A2[tid]; sab[tid] = ab1[tid]; }
    __syncthreads();
    int lane = tid & 63;
    int wib = tid >> 6;
    int wid = blockIdx.x * 4 + wib;
    int nw = gridDim.x * 4;
    for (int i = wid; i < n; i += nw) {
        float u0 = x1A[(size_t)i * 64 + lane], u1 = x1B[(size_t)i * 64 + lane];
        float v0 = x2A[(size_t)i * 64 + lane], v1 = x2B[(size_t)i * 64 + lane];
        float acc1 = 0.f, acc2 = 0.f;
#pragma unroll 4
        for (int d = 0; d < 64; ++d) {
            float w = sA1[d * HATT + lane];
            acc1 = fmaf(__shfl(u0, d), w, acc1);
            acc2 = fmaf(__shfl(v0, d), w, acc2);
        }
#pragma unroll 4
        for (int d = 0; d < 64; ++d) {
            float w = sA1[(d + 64) * HATT + lane];
            acc1 = fmaf(__shfl(u1, d), w, acc1);
            acc2 = fmaf(__shfl(v1, d), w, acc2);
        }
        float t1 = tanhf(acc1 + sab[lane]) * sA2[lane];
        float t2 = tanhf(acc2 + sab[lane]) * sA2[lane];
        for (int off = 32; off; off >>= 1) {
            t1 += __shfl_xor(t1, off);
            t2 += __shfl_xor(t2, off);
        }
        float mx = fmaxf(t1, t2);
        float e1 = expf(t1 - mx), e2 = expf(t2 - mx);
        float inv = 1.f / (e1 + e2);
        float be1 = e1 * inv, be2 = e2 * inv;
        out[(size_t)i * DF + lane] = be1 * u0 + be2 * v0;
        out[(size_t)i * DF + 64 + lane] = be1 * u1 + be2 * v1;
    }
}

// ---------------- launch ----------------

extern "C" void kernel_launch(void* const* d_in, const int* in_sizes, int n_in,
                              void* d_out, int out_size, void* d_ws, size_t ws_size,
                              hipStream_t stream) {
    const float* x  = (const float*)d_in[0];
    const int* row  = (const int*)d_in[1];
    const int* col  = (const int*)d_in[2];
    const float* W1 = (const float*)d_in[3];
    const float* b1 = (const float*)d_in[4];
    const float* W2 = (const float*)d_in[5];
    const float* b2 = (const float*)d_in[6];
    const float* A1 = (const float*)d_in[7];
    const float* ab1= (const float*)d_in[8];
    const float* A2 = (const float*)d_in[9];
    const int N = in_sizes[0] / DF;
    const int E = in_sizes[1];
    float* out = (float*)d_out;

    char* p = (char*)d_ws;
    auto alloc_b = [&](size_t bytes) -> char* {
        char* r = p;
        p += (bytes + 255) & ~(size_t)255;
        return r;
    };
    float* xA    = (float*)alloc_b((size_t)N * 64 * 4);
    float* xB    = (float*)alloc_b((size_t)N * 64 * 4);
    unsigned short* hA  = (unsigned short*)alloc_b((size_t)N * 64 * 2);  // bf16, also h1A
    unsigned short* hB  = (unsigned short*)alloc_b((size_t)N * 64 * 2);  // bf16, also h1B
    unsigned short* h2A = (unsigned short*)alloc_b((size_t)N * 64 * 2);
    unsigned short* h2B = (unsigned short*)alloc_b((size_t)N * 64 * 2);
    float* x1A   = (float*)alloc_b((size_t)N * 64 * 4);
    float* x1B   = (float*)alloc_b((size_t)N * 64 * 4);
    float* x2A   = (float*)alloc_b((size_t)N * 64 * 4);
    float* x2B   = (float*)alloc_b((size_t)N * 64 * 4);
    float* wsA   = (float*)alloc_b((size_t)E * 4);
    float* wsB   = (float*)alloc_b((size_t)E * 4);
    float* dp0   = (float*)alloc_b((size_t)E * 4);
    float* dp1   = (float*)alloc_b((size_t)E * 4);
    float* disA  = (float*)alloc_b((size_t)N * 4);
    float* disB  = (float*)alloc_b((size_t)N * 4);
    float* sqnx  = (float*)alloc_b((size_t)N * 4);
    float* sqn1  = (float*)alloc_b((size_t)N * 4);
    float* sqn2  = (float*)alloc_b((size_t)N * 4);
    int* cnt2    = (int*)alloc_b((size_t)SL * N * 4);
    int* tot     = (int*)alloc_b((size_t)N * 4);
    int* rowptr  = (int*)alloc_b((size_t)(N + 1) * 4);
    unsigned short* col_s = (unsigned short*)alloc_b((size_t)E * 2);
    (void)ws_size; (void)n_in; (void)out_size;

    const int nodeBlocks  = divup(N * 64, 256);   // 2500
    const int pairBlocks  = 2 * nodeBlocks;       // 5000
    const int mmBlocks    = divup(divup(N, 4), 4);
    const int mm2Blocks   = 2 * mmBlocks;
    const int ranges = divup(N, RPB);
    const int rpb    = divup(N, ranges);
    int es = divup(E, SL); es = (es + 3) & ~3;
    const int prepBlocks = ranges * SL;

    // graph prep
    hist2_kernel<<<prepBlocks, 256, 0, stream>>>(row, cnt2, E, N, ranges, rpb, es);
    split_x_kernel<<<nodeBlocks, 256, 0, stream>>>(x, xA, xB, sqnx, N);
    scanRT_kernel<<<divup(N, 64), 256, 0, stream>>>(cnt2, tot, N);
    scanT_kernel<<<1, 1024, 0, stream>>>(tot, rowptr, N);
    scatter2_kernel<<<prepBlocks, 256, 0, stream>>>(row, col, cnt2, rowptr, col_s, E, N, ranges, rpb, es);

    // shared layer-1 transform -> bf16 h
    mm_kernel<<<mmBlocks, 256, 0, stream>>>(x, x + 64, DF, W1, hA, hB, N);

    // layer-1 edge weights (fp32 chain) + fused degrees
    edgewA_kernel<<<nodeBlocks, 256, 0, stream>>>(xA, col_s, rowptr, dp0, N);
    edgewB1_kernel<<<nodeBlocks, 256, 0, stream>>>(xB, sqnx, col_s, rowptr, dp0,
                                                   wsA, wsB, disA, disB, N);

    // layer-1 dual SpMM: one wave per node, both halves + both branches
    spmm_l1_kernel<<<nodeBlocks, 256, 0, stream>>>(hA, hB, wsA, wsB, col_s, disA, disB,
                                                   rowptr, b1, x1A, x1B, x2A, x2B,
                                                   sqn1, sqn2, N);

    // layer-2 edge weights, both branches paired (fp32 chain)
    edgewA2_kernel<<<pairBlocks, 256, 0, stream>>>(x1A, x2A, col_s, rowptr, dp0, dp1, N);
    edgewB2_kernel<<<pairBlocks, 256, 0, stream>>>(x1B, x2B, sqn1, sqn2,
                                                   col_s, rowptr, dp0, dp1,
                                                   wsA, wsB, disA, disB, N);

    // layer-2 transforms, both branches paired -> bf16 h
    mm2_kernel<<<mm2Blocks, 256, 0, stream>>>(x1A, x1B, x2A, x2B, W2, hA, hB, h2A, h2B, N);

    // layer-2 SpMM: branch parity, both halves per wave
    spmm2d_kernel<<<pairBlocks, 256, 0, stream>>>(hA, hB, h2A, h2B, wsA, wsB, col_s,
                                                  disA, disB, rowptr, b2,
                                                  x1A, x1B, x2A, x2B, N);

    // semantic attention fusion -> out
    attn_kernel<<<divup(N, 4), 256, 0, stream>>>(x1A, x1B, x2A, x2B, A1, ab1, A2, out, N);
}